// Round 5
// baseline (7739.308 us; speedup 1.0000x reference)
//
#include <hip/hip_runtime.h>
#include <hip/hip_bf16.h>

#define BS   2
#define PP   512
#define NN   2048
#define DD   768
#define HH   12
#define HD   64
#define RTOT 2560   // P + N rows per batch
#define QKVC 2304   // 3*D

__device__ __forceinline__ float bf2f(unsigned short x) {
    union { unsigned u; float f; } c; c.u = ((unsigned)x) << 16; return c.f;
}
__device__ __forceinline__ unsigned short f2bf(float x) {
    union { float f; unsigned u; } c; c.f = x;
    unsigned r = c.u + 0x7fff + ((c.u >> 16) & 1);   // RNE
    return (unsigned short)(r >> 16);
}
// unpack 8 bf16 (one uint4) -> 8 floats
__device__ __forceinline__ void bf8_to_f(uint4 v, float* f) {
    f[0] = bf2f(v.x & 0xffff); f[1] = bf2f(v.x >> 16);
    f[2] = bf2f(v.y & 0xffff); f[3] = bf2f(v.y >> 16);
    f[4] = bf2f(v.z & 0xffff); f[5] = bf2f(v.z >> 16);
    f[6] = bf2f(v.w & 0xffff); f[7] = bf2f(v.w >> 16);
}

// Runtime-dtype loads (f32 vs bf16). Branch is wave-uniform.
__device__ __forceinline__ float4 load4(const void* p, size_t i, bool f32) {
    if (f32) return *(const float4*)((const float*)p + i);
    ushort4 u = *(const ushort4*)((const unsigned short*)p + i);
    return make_float4(bf2f(u.x), bf2f(u.y), bf2f(u.z), bf2f(u.w));
}
__device__ __forceinline__ float load1(const void* p, size_t i, bool f32) {
    return f32 ? ((const float*)p)[i] : bf2f(((const unsigned short*)p)[i]);
}
// Mask read with runtime type: 0 = int32, 1 = packed u8, 2 = float32
__device__ __forceinline__ bool mask_at(const void* m, int idx, int mtype) {
    if (mtype == 2) return ((const float*)m)[idx] != 0.0f;
    if (mtype == 1) return ((const unsigned char*)m)[idx] != 0;
    return ((const int*)m)[idx] != 0;
}
__device__ __forceinline__ void store_out(float* p, size_t i, float v) { p[i] = v; }
__device__ __forceinline__ void store_out(__hip_bfloat16* p, size_t i, float v) {
    p[i] = __float2bfloat16(v);
}

// ---------------------------------------------------------------------------
// Runtime dtype detection (graph-safe). flags[0]: inputs f32?  flags[1]: mask type
// ---------------------------------------------------------------------------
__global__ void detect_kernel(const void* __restrict__ w,
                              const void* __restrict__ mask,
                              int* __restrict__ flags) {
    __shared__ int s_f32, s_fmask, s_bmask;
    if (threadIdx.x == 0) { s_f32 = 0; s_fmask = 0; s_bmask = 0; }
    __syncthreads();
    const unsigned short* u = (const unsigned short*)w;
    int bad = 0;
    for (int i = threadIdx.x * 2; i < 65536; i += 512) {
        float v = bf2f(u[i]);
        if (!(fabsf(v) <= 2.0f)) bad = 1;
    }
    if (bad) atomicOr(&s_f32, 1);
    const unsigned* mw = (const unsigned*)mask;
    int fm = 0, bm = 0;
    for (int i = threadIdx.x; i < 256; i += 256) {
        unsigned v = mw[i];
        if (v == 0x3F800000u) fm = 1;
        else if ((v & 0xFFFFFF00u) != 0u) bm = 1;
    }
    if (fm) atomicOr(&s_fmask, 1);
    if (bm) atomicOr(&s_bmask, 1);
    __syncthreads();
    if (threadIdx.x == 0) {
        flags[0] = s_f32;
        flags[1] = s_fmask ? 2 : (s_bmask ? 1 : 0);
    }
}

// ---------------------------------------------------------------------------
// 64x64-tile GEMM (unchanged from passing round-4 version).
// ---------------------------------------------------------------------------
template<int MODE, int NCOL, typename OutT>
__global__ __launch_bounds__(256) void gemm_kernel(
    const void* __restrict__ A0, const void* __restrict__ A1,
    const void* __restrict__ W, const void* __restrict__ bias,
    const int* __restrict__ flags, OutT* __restrict__ out)
{
    const bool f32 = flags[0] != 0;
    alignas(16) __shared__ float As[16][68];
    alignas(16) __shared__ float Bsh[16][68];
    const int tid  = threadIdx.x;
    const int row0 = blockIdx.y * 64;
    const int col0 = blockIdx.x * 64;
    const int ty = tid >> 4, tx = tid & 15;
    const int a_row = tid >> 2;
    const int a_k4  = (tid & 3) * 4;
    const int grow  = row0 + a_row;
    const void* abase; size_t aoff; bool af32;
    if (MODE == 0) {
        int b = grow / RTOT, r = grow % RTOT;
        if (r < NN) { abase = A0; aoff = (size_t)(b * NN + r) * DD; }
        else        { abase = A1; aoff = (size_t)(b * PP + (r - NN)) * DD; }
        af32 = f32;
    } else {
        abase = A0; aoff = (size_t)grow * DD; af32 = false;
    }
    const int b_k  = tid >> 4;
    const int b_n4 = (tid & 15) * 4;
    float acc[4][4] = {};
    for (int k0 = 0; k0 < DD; k0 += 16) {
        float4 fa = load4(abase, aoff + k0 + a_k4, af32);
        As[a_k4 + 0][a_row] = fa.x;
        As[a_k4 + 1][a_row] = fa.y;
        As[a_k4 + 2][a_row] = fa.z;
        As[a_k4 + 3][a_row] = fa.w;
        float4 fb = load4(W, (size_t)(k0 + b_k) * NCOL + col0 + b_n4, f32);
        *(float4*)&Bsh[b_k][b_n4] = fb;
        __syncthreads();
        #pragma unroll
        for (int kk = 0; kk < 16; kk++) {
            float4 av = *(const float4*)&As[kk][ty * 4];
            float4 bv = *(const float4*)&Bsh[kk][tx * 4];
            float a_[4] = {av.x, av.y, av.z, av.w};
            float b_[4] = {bv.x, bv.y, bv.z, bv.w};
            #pragma unroll
            for (int i = 0; i < 4; i++)
                #pragma unroll
                for (int j = 0; j < 4; j++)
                    acc[i][j] += a_[i] * b_[j];
        }
        __syncthreads();
    }
    #pragma unroll
    for (int i = 0; i < 4; i++) {
        int gr = row0 + ty * 4 + i;
        #pragma unroll
        for (int j = 0; j < 4; j++) {
            int gc = col0 + tx * 4 + j;
            float v = acc[i][j] + load1(bias, gc, f32);
            if (MODE == 0) {
                store_out(out, (size_t)gr * NCOL + gc, v);
            } else {
                int b = gr / RTOT, r = gr % RTOT;
                size_t dst = (r < PP)
                    ? ((size_t)(b * PP + r) * DD + gc)
                    : ((size_t)BS * PP * DD + (size_t)(b * NN + (r - PP)) * DD + gc);
                store_out(out, dst, v);
            }
        }
    }
}

// ---------------------------------------------------------------------------
// Flash-style tiled attention. Block = 256 thr = 64 queries of one (b,h).
// K-tiles of 64 keys staged in LDS (K transposed, V natural), online softmax,
// P via LDS (bf16), 4x4 register tile per thread.
// MODE 0 = cross (queries rows 512..2559, keys rows 0..2559)
// MODE 1 = self  (queries rows 0..511, keys rows 0..511, scrambled store)
// ---------------------------------------------------------------------------
template<int MODE>
__global__ __launch_bounds__(256, 2) void fattn_kernel(
    const __hip_bfloat16* __restrict__ qkv,
    const void* __restrict__ mask,
    const int* __restrict__ flags,
    __hip_bfloat16* __restrict__ attn_out)
{
    constexpr int NQ    = (MODE == 0) ? NN : PP;
    constexpr int NK    = (MODE == 0) ? RTOT : PP;
    constexpr int QOFF  = (MODE == 0) ? PP : 0;
    constexpr int NTILE = NK / 64;

    __shared__ float Qs[64][68];           // Qs[r][d]
    __shared__ float Kt[64][68];           // Kt[d][c]  (transposed)
    __shared__ float Vs[64][68];           // Vs[c][d]
    __shared__ unsigned short Ps[64][68];  // P tile, bf16

    const int tid = threadIdx.x;
    const int ty = tid >> 4;      // 0..15 -> rows ty*4..+3
    const int tx = tid & 15;      // 0..15 -> cols tx*4..+3
    const int nqb = NQ / 64;
    const int q0 = (blockIdx.x % nqb) * 64;
    const int h  = (blockIdx.x / nqb) % HH;
    const int b  = blockIdx.x / (nqb * HH);
    const int mtype = flags[1];

    const int lr  = tid >> 2;          // staging row 0..63
    const int ld0 = (tid & 3) << 4;    // staging d-offset 0,16,32,48

    // ---- load Q tile ----
    {
        const unsigned short* qp = (const unsigned short*)qkv +
            (size_t)(b * RTOT + QOFF + q0 + lr) * QKVC + h * HD + ld0;
        float f[8];
        #pragma unroll
        for (int hf = 0; hf < 2; hf++) {
            bf8_to_f(*(const uint4*)(qp + hf * 8), f);
            *(float4*)&Qs[lr][ld0 + hf * 8]     = make_float4(f[0], f[1], f[2], f[3]);
            *(float4*)&Qs[lr][ld0 + hf * 8 + 4] = make_float4(f[4], f[5], f[6], f[7]);
        }
    }

    float o[4][4] = {};
    float mrun[4] = {-3e38f, -3e38f, -3e38f, -3e38f};
    float lrun[4] = {};
    __syncthreads();

    for (int t = 0; t < NTILE; t++) {
        const int m0 = t * 64;
        // ---- stage K (transposed) and V ----
        {
            const unsigned short* kp = (const unsigned short*)qkv +
                (size_t)(b * RTOT + m0 + lr) * QKVC + DD + h * HD + ld0;
            float f[8];
            #pragma unroll
            for (int hf = 0; hf < 2; hf++) {
                bf8_to_f(*(const uint4*)(kp + hf * 8), f);
                #pragma unroll
                for (int k = 0; k < 8; k++) Kt[ld0 + hf * 8 + k][lr] = f[k];
            }
            const unsigned short* vp = kp + DD;
            #pragma unroll
            for (int hf = 0; hf < 2; hf++) {
                bf8_to_f(*(const uint4*)(vp + hf * 8), f);
                *(float4*)&Vs[lr][ld0 + hf * 8]     = make_float4(f[0], f[1], f[2], f[3]);
                *(float4*)&Vs[lr][ld0 + hf * 8 + 4] = make_float4(f[4], f[5], f[6], f[7]);
            }
        }
        __syncthreads();

        // ---- mask bits for this thread's 4 key columns ----
        bool mk[4];
        #pragma unroll
        for (int j = 0; j < 4; j++) {
            int m = m0 + tx * 4 + j;
            mk[j] = (m < PP) && mask_at(mask, b * PP + m, mtype);
        }

        // ---- S = Q K^T (4x4 per thread) ----
        float s[4][4] = {};
        #pragma unroll
        for (int d0 = 0; d0 < HD; d0 += 4) {
            float qa[4][4], kk[4][4];
            #pragma unroll
            for (int i = 0; i < 4; i++) {
                float4 qv = *(const float4*)&Qs[ty * 4 + i][d0];
                qa[i][0] = qv.x; qa[i][1] = qv.y; qa[i][2] = qv.z; qa[i][3] = qv.w;
            }
            #pragma unroll
            for (int tt = 0; tt < 4; tt++) {
                float4 kv = *(const float4*)&Kt[d0 + tt][tx * 4];
                kk[tt][0] = kv.x; kk[tt][1] = kv.y; kk[tt][2] = kv.z; kk[tt][3] = kv.w;
            }
            #pragma unroll
            for (int i = 0; i < 4; i++)
                #pragma unroll
                for (int j = 0; j < 4; j++)
                    s[i][j] += qa[i][0] * kk[0][j] + qa[i][1] * kk[1][j]
                             + qa[i][2] * kk[2][j] + qa[i][3] * kk[3][j];
        }
        #pragma unroll
        for (int i = 0; i < 4; i++)
            #pragma unroll
            for (int j = 0; j < 4; j++)
                s[i][j] = mk[j] ? -1e30f : s[i][j] * 0.125f;

        // ---- online softmax update (row reduce across 16 lanes) ----
        #pragma unroll
        for (int i = 0; i < 4; i++) {
            float tm = fmaxf(fmaxf(s[i][0], s[i][1]), fmaxf(s[i][2], s[i][3]));
            #pragma unroll
            for (int off = 1; off < 16; off <<= 1)
                tm = fmaxf(tm, __shfl_xor(tm, off));
            float mnew = fmaxf(mrun[i], tm);
            float al = __expf(mrun[i] - mnew);
            float p0 = (s[i][0] < -1e29f) ? 0.f : __expf(s[i][0] - mnew);
            float p1 = (s[i][1] < -1e29f) ? 0.f : __expf(s[i][1] - mnew);
            float p2 = (s[i][2] < -1e29f) ? 0.f : __expf(s[i][2] - mnew);
            float p3 = (s[i][3] < -1e29f) ? 0.f : __expf(s[i][3] - mnew);
            float ts = p0 + p1 + p2 + p3;
            #pragma unroll
            for (int off = 1; off < 16; off <<= 1)
                ts += __shfl_xor(ts, off);
            mrun[i] = mnew;
            lrun[i] = lrun[i] * al + ts;
            o[i][0] *= al; o[i][1] *= al; o[i][2] *= al; o[i][3] *= al;
            ushort4 pu;
            pu.x = f2bf(p0); pu.y = f2bf(p1); pu.z = f2bf(p2); pu.w = f2bf(p3);
            *(ushort4*)&Ps[ty * 4 + i][tx * 4] = pu;
        }
        __syncthreads();

        // ---- O += P V ----
        #pragma unroll
        for (int c0 = 0; c0 < 64; c0 += 4) {
            float pf[4][4], vv[4][4];
            #pragma unroll
            for (int i = 0; i < 4; i++) {
                ushort4 pu = *(const ushort4*)&Ps[ty * 4 + i][c0];
                pf[i][0] = bf2f(pu.x); pf[i][1] = bf2f(pu.y);
                pf[i][2] = bf2f(pu.z); pf[i][3] = bf2f(pu.w);
            }
            #pragma unroll
            for (int tt = 0; tt < 4; tt++) {
                float4 v = *(const float4*)&Vs[c0 + tt][tx * 4];
                vv[tt][0] = v.x; vv[tt][1] = v.y; vv[tt][2] = v.z; vv[tt][3] = v.w;
            }
            #pragma unroll
            for (int i = 0; i < 4; i++)
                #pragma unroll
                for (int j = 0; j < 4; j++)
                    o[i][j] += pf[i][0] * vv[0][j] + pf[i][1] * vv[1][j]
                             + pf[i][2] * vv[2][j] + pf[i][3] * vv[3][j];
        }
        __syncthreads();   // before next tile's staging overwrites Kt/Vs/Ps
    }

    // ---- epilogue ----
    #pragma unroll
    for (int i = 0; i < 4; i++) {
        float inv = 1.0f / lrun[i];
        if (MODE == 0) {
            size_t row = (size_t)(b * RTOT + PP + q0 + ty * 4 + i);
            ushort4 u;
            u.x = f2bf(o[i][0] * inv); u.y = f2bf(o[i][1] * inv);
            u.z = f2bf(o[i][2] * inv); u.w = f2bf(o[i][3] * inv);
            *(ushort4*)((unsigned short*)attn_out + row * DD + h * HD + tx * 4) = u;
        } else {
            int p_ = q0 + ty * 4 + i;
            #pragma unroll
            for (int j = 0; j < 4; j++) {
                int dc = tx * 4 + j;
                int f = h * (HD * PP) + dc * PP + p_;
                ((unsigned short*)attn_out)[(size_t)(b * RTOT + f / DD) * DD + (f % DD)]
                    = f2bf(o[i][j] * inv);
            }
        }
    }
}

// ---------------------------------------------------------------------------
extern "C" void kernel_launch(void* const* d_in, const int* in_sizes, int n_in,
                              void* d_out, int out_size, void* d_ws, size_t ws_size,
                              hipStream_t stream) {
    const void *xs = nullptr, *xq = nullptr, *mask = nullptr,
               *qkv_w = nullptr, *qkv_b = nullptr, *proj_w = nullptr, *proj_b = nullptr;
    for (int i = 0; i < n_in; i++) {
        switch (in_sizes[i]) {
            case BS * PP * DD:   xs     = d_in[i]; break;
            case BS * NN * DD:   xq     = d_in[i]; break;
            case BS * PP:        mask   = d_in[i]; break;
            case DD * QKVC:      qkv_w  = d_in[i]; break;
            case QKVC:           qkv_b  = d_in[i]; break;
            case DD * DD:        proj_w = d_in[i]; break;
            case DD:             proj_b = d_in[i]; break;
        }
    }
    if (!xs || !xq || !mask || !qkv_w || !qkv_b || !proj_w || !proj_b) {
        xs = d_in[0]; xq = d_in[1]; mask = d_in[2];
        qkv_w = d_in[3]; qkv_b = d_in[4]; proj_w = d_in[5]; proj_b = d_in[6];
    }

    float* out = (float*)d_out;   // reference output dtype is float32

    int* flags = (int*)d_ws;
    __hip_bfloat16* fullqkv = (__hip_bfloat16*)((char*)d_ws + 256); // [BS*2560, 2304]
    __hip_bfloat16* attn    = fullqkv + (size_t)BS * RTOT * QKVC;   // [BS*2560, 768]

    detect_kernel<<<1, 256, 0, stream>>>(qkv_w, mask, flags);

    // 1) fullqkv = concat([xq, xs]) @ qkv_w + qkv_b
    gemm_kernel<0, QKVC, __hip_bfloat16>
        <<<dim3(QKVC / 64, BS * RTOT / 64), 256, 0, stream>>>(
        xq, xs, qkv_w, qkv_b, flags, fullqkv);

    // 2) cross attention (flash) -> attn rows 512..2559
    fattn_kernel<0><<<BS * HH * (NN / 64), 256, 0, stream>>>(fullqkv, mask, flags, attn);

    // 3) self attention (flash, scrambled) -> attn rows 0..511
    fattn_kernel<1><<<BS * HH * (PP / 64), 256, 0, stream>>>(fullqkv, mask, flags, attn);

    // 4) out = attn @ proj_w + proj_b (float32 out)
    gemm_kernel<1, DD, float>
        <<<dim3(DD / 64, BS * RTOT / 64), 256, 0, stream>>>(
        attn, nullptr, proj_w, proj_b, flags, out);
}

// Round 7
// 1040.542 us; speedup vs baseline: 7.4378x; 7.4378x over previous
//
#include <hip/hip_runtime.h>
#include <hip/hip_bf16.h>

#define BS   2
#define PP   512
#define NN   2048
#define DD   768
#define HH   12
#define HD   64
#define RTOT 2560   // P + N rows per batch
#define QKVC 2304   // 3*D

__device__ __forceinline__ float bf2f(unsigned short x) {
    union { unsigned u; float f; } c; c.u = ((unsigned)x) << 16; return c.f;
}
__device__ __forceinline__ unsigned short f2bf(float x) {
    union { float f; unsigned u; } c; c.f = x;
    unsigned r = c.u + 0x7fff + ((c.u >> 16) & 1);   // RNE
    return (unsigned short)(r >> 16);
}
// unpack 8 bf16 (one uint4) -> 8 floats
__device__ __forceinline__ void bf8_to_f(uint4 v, float* f) {
    f[0] = bf2f(v.x & 0xffff); f[1] = bf2f(v.x >> 16);
    f[2] = bf2f(v.y & 0xffff); f[3] = bf2f(v.y >> 16);
    f[4] = bf2f(v.z & 0xffff); f[5] = bf2f(v.z >> 16);
    f[6] = bf2f(v.w & 0xffff); f[7] = bf2f(v.w >> 16);
}

// Runtime-dtype loads (f32 vs bf16). Branch is wave-uniform.
__device__ __forceinline__ float4 load4(const void* p, size_t i, bool f32) {
    if (f32) return *(const float4*)((const float*)p + i);
    ushort4 u = *(const ushort4*)((const unsigned short*)p + i);
    return make_float4(bf2f(u.x), bf2f(u.y), bf2f(u.z), bf2f(u.w));
}
__device__ __forceinline__ float load1(const void* p, size_t i, bool f32) {
    return f32 ? ((const float*)p)[i] : bf2f(((const unsigned short*)p)[i]);
}
// Mask read with runtime type: 0 = int32, 1 = packed u8, 2 = float32
__device__ __forceinline__ bool mask_at(const void* m, int idx, int mtype) {
    if (mtype == 2) return ((const float*)m)[idx] != 0.0f;
    if (mtype == 1) return ((const unsigned char*)m)[idx] != 0;
    return ((const int*)m)[idx] != 0;
}
__device__ __forceinline__ void store_out(float* p, size_t i, float v) { p[i] = v; }
__device__ __forceinline__ void store_out(__hip_bfloat16* p, size_t i, float v) {
    p[i] = __float2bfloat16(v);
}

// ---------------------------------------------------------------------------
// Runtime dtype detection (graph-safe). flags[0]: inputs f32?  flags[1]: mask type
// ---------------------------------------------------------------------------
__global__ void detect_kernel(const void* __restrict__ w,
                              const void* __restrict__ mask,
                              int* __restrict__ flags) {
    __shared__ int s_f32, s_fmask, s_bmask;
    if (threadIdx.x == 0) { s_f32 = 0; s_fmask = 0; s_bmask = 0; }
    __syncthreads();
    const unsigned short* u = (const unsigned short*)w;
    int bad = 0;
    for (int i = threadIdx.x * 2; i < 65536; i += 512) {
        float v = bf2f(u[i]);
        if (!(fabsf(v) <= 2.0f)) bad = 1;
    }
    if (bad) atomicOr(&s_f32, 1);
    const unsigned* mw = (const unsigned*)mask;
    int fm = 0, bm = 0;
    for (int i = threadIdx.x; i < 256; i += 256) {
        unsigned v = mw[i];
        if (v == 0x3F800000u) fm = 1;
        else if ((v & 0xFFFFFF00u) != 0u) bm = 1;
    }
    if (fm) atomicOr(&s_fmask, 1);
    if (bm) atomicOr(&s_bmask, 1);
    __syncthreads();
    if (threadIdx.x == 0) {
        flags[0] = s_f32;
        flags[1] = s_fmask ? 2 : (s_bmask ? 1 : 0);
    }
}

// ---------------------------------------------------------------------------
// 64x64-tile GEMM (unchanged — correct and not yet the bottleneck).
// ---------------------------------------------------------------------------
template<int MODE, int NCOL, typename OutT>
__global__ __launch_bounds__(256) void gemm_kernel(
    const void* __restrict__ A0, const void* __restrict__ A1,
    const void* __restrict__ W, const void* __restrict__ bias,
    const int* __restrict__ flags, OutT* __restrict__ out)
{
    const bool f32 = flags[0] != 0;
    alignas(16) __shared__ float As[16][68];
    alignas(16) __shared__ float Bsh[16][68];
    const int tid  = threadIdx.x;
    const int row0 = blockIdx.y * 64;
    const int col0 = blockIdx.x * 64;
    const int ty = tid >> 4, tx = tid & 15;
    const int a_row = tid >> 2;
    const int a_k4  = (tid & 3) * 4;
    const int grow  = row0 + a_row;
    const void* abase; size_t aoff; bool af32;
    if (MODE == 0) {
        int b = grow / RTOT, r = grow % RTOT;
        if (r < NN) { abase = A0; aoff = (size_t)(b * NN + r) * DD; }
        else        { abase = A1; aoff = (size_t)(b * PP + (r - NN)) * DD; }
        af32 = f32;
    } else {
        abase = A0; aoff = (size_t)grow * DD; af32 = false;
    }
    const int b_k  = tid >> 4;
    const int b_n4 = (tid & 15) * 4;
    float acc[4][4] = {};
    for (int k0 = 0; k0 < DD; k0 += 16) {
        float4 fa = load4(abase, aoff + k0 + a_k4, af32);
        As[a_k4 + 0][a_row] = fa.x;
        As[a_k4 + 1][a_row] = fa.y;
        As[a_k4 + 2][a_row] = fa.z;
        As[a_k4 + 3][a_row] = fa.w;
        float4 fb = load4(W, (size_t)(k0 + b_k) * NCOL + col0 + b_n4, f32);
        *(float4*)&Bsh[b_k][b_n4] = fb;
        __syncthreads();
        #pragma unroll
        for (int kk = 0; kk < 16; kk++) {
            float4 av = *(const float4*)&As[kk][ty * 4];
            float4 bv = *(const float4*)&Bsh[kk][tx * 4];
            float a_[4] = {av.x, av.y, av.z, av.w};
            float b_[4] = {bv.x, bv.y, bv.z, bv.w};
            #pragma unroll
            for (int i = 0; i < 4; i++)
                #pragma unroll
                for (int j = 0; j < 4; j++)
                    acc[i][j] += a_[i] * b_[j];
        }
        __syncthreads();
    }
    #pragma unroll
    for (int i = 0; i < 4; i++) {
        int gr = row0 + ty * 4 + i;
        #pragma unroll
        for (int j = 0; j < 4; j++) {
            int gc = col0 + tx * 4 + j;
            float v = acc[i][j] + load1(bias, gc, f32);
            if (MODE == 0) {
                store_out(out, (size_t)gr * NCOL + gc, v);
            } else {
                int b = gr / RTOT, r = gr % RTOT;
                size_t dst = (r < PP)
                    ? ((size_t)(b * PP + r) * DD + gc)
                    : ((size_t)BS * PP * DD + (size_t)(b * NN + (r - PP)) * DD + gc);
                store_out(out, dst, v);
            }
        }
    }
}

// ---------------------------------------------------------------------------
// Flash-style tiled attention, register-lean (anti-spill).
// Block = 256 thr = 64 queries of one (b,h). K-tiles of 64 in LDS.
// Qs kept as raw bf16; K/V staged f32; streaming inner loops w/ unroll-2.
// FIX (r6): Q staging now copies BOTH uint4 halves (16 bf16/thread) —
// round-6's single-uint4 copy left half of Qs uninitialized -> NaN.
// ---------------------------------------------------------------------------
template<int MODE>
__global__ __launch_bounds__(256) void fattn_kernel(
    const __hip_bfloat16* __restrict__ qkv,
    const void* __restrict__ mask,
    const int* __restrict__ flags,
    __hip_bfloat16* __restrict__ attn_out)
{
    constexpr int NQ    = (MODE == 0) ? NN : PP;
    constexpr int NK    = (MODE == 0) ? RTOT : PP;
    constexpr int QOFF  = (MODE == 0) ? PP : 0;
    constexpr int NTILE = NK / 64;

    alignas(16) __shared__ unsigned short Qs[64][72];  // raw bf16, [r][d]
    alignas(16) __shared__ float Kt[64][68];           // Kt[d][c]  (transposed)
    alignas(16) __shared__ float Vs[64][68];           // Vs[c][d]
    alignas(16) __shared__ unsigned short Ps[64][68];  // P tile, bf16

    const int tid = threadIdx.x;
    const int ty = tid >> 4;      // 0..15 -> rows ty*4..+3
    const int tx = tid & 15;      // 0..15 -> cols tx*4..+3
    const int nqb = NQ / 64;
    const int q0 = (blockIdx.x % nqb) * 64;
    const int h  = (blockIdx.x / nqb) % HH;
    const int b  = blockIdx.x / (nqb * HH);
    const int mtype = flags[1];

    const int lr  = tid >> 2;          // staging row 0..63
    const int ld0 = (tid & 3) << 4;    // staging d-offset 0,16,32,48

    // ---- load Q tile (raw bf16 copy: 16 elements = two uint4 per thread) ----
    {
        const unsigned short* qp = (const unsigned short*)qkv +
            (size_t)(b * RTOT + QOFF + q0 + lr) * QKVC + h * HD + ld0;
        *(uint4*)&Qs[lr][ld0]     = *(const uint4*)qp;
        *(uint4*)&Qs[lr][ld0 + 8] = *(const uint4*)(qp + 8);
    }

    float o[4][4] = {};
    float mrun[4] = {-3e38f, -3e38f, -3e38f, -3e38f};
    float lrun[4] = {};
    __syncthreads();

    for (int t = 0; t < NTILE; t++) {
        const int m0 = t * 64;
        // ---- stage K (transposed, f32) and V (natural, f32) ----
        {
            const unsigned short* kp = (const unsigned short*)qkv +
                (size_t)(b * RTOT + m0 + lr) * QKVC + DD + h * HD + ld0;
            float f[8];
            #pragma unroll
            for (int hf = 0; hf < 2; hf++) {
                bf8_to_f(*(const uint4*)(kp + hf * 8), f);
                #pragma unroll
                for (int k = 0; k < 8; k++) Kt[ld0 + hf * 8 + k][lr] = f[k];
            }
            const unsigned short* vp = kp + DD;
            #pragma unroll
            for (int hf = 0; hf < 2; hf++) {
                bf8_to_f(*(const uint4*)(vp + hf * 8), f);
                *(float4*)&Vs[lr][ld0 + hf * 8]     = make_float4(f[0], f[1], f[2], f[3]);
                *(float4*)&Vs[lr][ld0 + hf * 8 + 4] = make_float4(f[4], f[5], f[6], f[7]);
            }
        }
        __syncthreads();

        // ---- S = Q K^T (4x4 per thread), streaming fragments ----
        float s[4][4] = {};
        #pragma unroll 2
        for (int d0 = 0; d0 < HD; d0 += 4) {
            float4 k0 = *(const float4*)&Kt[d0 + 0][tx * 4];
            float4 k1 = *(const float4*)&Kt[d0 + 1][tx * 4];
            float4 k2 = *(const float4*)&Kt[d0 + 2][tx * 4];
            float4 k3 = *(const float4*)&Kt[d0 + 3][tx * 4];
            #pragma unroll
            for (int i = 0; i < 4; i++) {
                ushort4 qu = *(const ushort4*)&Qs[ty * 4 + i][d0];
                float q0f = bf2f(qu.x), q1f = bf2f(qu.y);
                float q2f = bf2f(qu.z), q3f = bf2f(qu.w);
                s[i][0] += q0f * k0.x + q1f * k1.x + q2f * k2.x + q3f * k3.x;
                s[i][1] += q0f * k0.y + q1f * k1.y + q2f * k2.y + q3f * k3.y;
                s[i][2] += q0f * k0.z + q1f * k1.z + q2f * k2.z + q3f * k3.z;
                s[i][3] += q0f * k0.w + q1f * k1.w + q2f * k2.w + q3f * k3.w;
            }
        }

        // ---- mask + scale ----
        #pragma unroll
        for (int j = 0; j < 4; j++) {
            int m = m0 + tx * 4 + j;
            bool mk = (m < PP) && mask_at(mask, b * PP + m, mtype);
            #pragma unroll
            for (int i = 0; i < 4; i++)
                s[i][j] = mk ? -1e30f : s[i][j] * 0.125f;
        }

        // ---- online softmax update (row reduce across 16 lanes) ----
        #pragma unroll
        for (int i = 0; i < 4; i++) {
            float tm = fmaxf(fmaxf(s[i][0], s[i][1]), fmaxf(s[i][2], s[i][3]));
            #pragma unroll
            for (int off = 1; off < 16; off <<= 1)
                tm = fmaxf(tm, __shfl_xor(tm, off));
            float mnew = fmaxf(mrun[i], tm);
            float al = __expf(mrun[i] - mnew);
            float p0 = (s[i][0] < -1e29f) ? 0.f : __expf(s[i][0] - mnew);
            float p1 = (s[i][1] < -1e29f) ? 0.f : __expf(s[i][1] - mnew);
            float p2 = (s[i][2] < -1e29f) ? 0.f : __expf(s[i][2] - mnew);
            float p3 = (s[i][3] < -1e29f) ? 0.f : __expf(s[i][3] - mnew);
            float ts = p0 + p1 + p2 + p3;
            #pragma unroll
            for (int off = 1; off < 16; off <<= 1)
                ts += __shfl_xor(ts, off);
            mrun[i] = mnew;
            lrun[i] = lrun[i] * al + ts;
            o[i][0] *= al; o[i][1] *= al; o[i][2] *= al; o[i][3] *= al;
            ushort4 pu;
            pu.x = f2bf(p0); pu.y = f2bf(p1); pu.z = f2bf(p2); pu.w = f2bf(p3);
            *(ushort4*)&Ps[ty * 4 + i][tx * 4] = pu;
        }
        __syncthreads();

        // ---- O += P V, streaming fragments ----
        #pragma unroll 2
        for (int c0 = 0; c0 < 64; c0 += 4) {
            float4 v0 = *(const float4*)&Vs[c0 + 0][tx * 4];
            float4 v1 = *(const float4*)&Vs[c0 + 1][tx * 4];
            float4 v2 = *(const float4*)&Vs[c0 + 2][tx * 4];
            float4 v3 = *(const float4*)&Vs[c0 + 3][tx * 4];
            #pragma unroll
            for (int i = 0; i < 4; i++) {
                ushort4 pu = *(const ushort4*)&Ps[ty * 4 + i][c0];
                float p0f = bf2f(pu.x), p1f = bf2f(pu.y);
                float p2f = bf2f(pu.z), p3f = bf2f(pu.w);
                o[i][0] += p0f * v0.x + p1f * v1.x + p2f * v2.x + p3f * v3.x;
                o[i][1] += p0f * v0.y + p1f * v1.y + p2f * v2.y + p3f * v3.y;
                o[i][2] += p0f * v0.z + p1f * v1.z + p2f * v2.z + p3f * v3.z;
                o[i][3] += p0f * v0.w + p1f * v1.w + p2f * v2.w + p3f * v3.w;
            }
        }
        __syncthreads();   // before next tile's staging overwrites Kt/Vs/Ps
    }

    // ---- epilogue ----
    #pragma unroll
    for (int i = 0; i < 4; i++) {
        float inv = 1.0f / lrun[i];
        if (MODE == 0) {
            size_t row = (size_t)(b * RTOT + PP + q0 + ty * 4 + i);
            ushort4 u;
            u.x = f2bf(o[i][0] * inv); u.y = f2bf(o[i][1] * inv);
            u.z = f2bf(o[i][2] * inv); u.w = f2bf(o[i][3] * inv);
            *(ushort4*)((unsigned short*)attn_out + row * DD + h * HD + tx * 4) = u;
        } else {
            int p_ = q0 + ty * 4 + i;
            #pragma unroll
            for (int j = 0; j < 4; j++) {
                int dc = tx * 4 + j;
                int f = h * (HD * PP) + dc * PP + p_;
                ((unsigned short*)attn_out)[(size_t)(b * RTOT + f / DD) * DD + (f % DD)]
                    = f2bf(o[i][j] * inv);
            }
        }
    }
}

// ---------------------------------------------------------------------------
extern "C" void kernel_launch(void* const* d_in, const int* in_sizes, int n_in,
                              void* d_out, int out_size, void* d_ws, size_t ws_size,
                              hipStream_t stream) {
    const void *xs = nullptr, *xq = nullptr, *mask = nullptr,
               *qkv_w = nullptr, *qkv_b = nullptr, *proj_w = nullptr, *proj_b = nullptr;
    for (int i = 0; i < n_in; i++) {
        switch (in_sizes[i]) {
            case BS * PP * DD:   xs     = d_in[i]; break;
            case BS * NN * DD:   xq     = d_in[i]; break;
            case BS * PP:        mask   = d_in[i]; break;
            case DD * QKVC:      qkv_w  = d_in[i]; break;
            case QKVC:           qkv_b  = d_in[i]; break;
            case DD * DD:        proj_w = d_in[i]; break;
            case DD:             proj_b = d_in[i]; break;
        }
    }
    if (!xs || !xq || !mask || !qkv_w || !qkv_b || !proj_w || !proj_b) {
        xs = d_in[0]; xq = d_in[1]; mask = d_in[2];
        qkv_w = d_in[3]; qkv_b = d_in[4]; proj_w = d_in[5]; proj_b = d_in[6];
    }

    float* out = (float*)d_out;   // reference output dtype is float32

    int* flags = (int*)d_ws;
    __hip_bfloat16* fullqkv = (__hip_bfloat16*)((char*)d_ws + 256); // [BS*2560, 2304]
    __hip_bfloat16* attn    = fullqkv + (size_t)BS * RTOT * QKVC;   // [BS*2560, 768]

    detect_kernel<<<1, 256, 0, stream>>>(qkv_w, mask, flags);

    // 1) fullqkv = concat([xq, xs]) @ qkv_w + qkv_b
    gemm_kernel<0, QKVC, __hip_bfloat16>
        <<<dim3(QKVC / 64, BS * RTOT / 64), 256, 0, stream>>>(
        xq, xs, qkv_w, qkv_b, flags, fullqkv);

    // 2) cross attention (flash) -> attn rows 512..2559
    fattn_kernel<0><<<BS * HH * (NN / 64), 256, 0, stream>>>(fullqkv, mask, flags, attn);

    // 3) self attention (flash, scrambled) -> attn rows 0..511
    fattn_kernel<1><<<BS * HH * (PP / 64), 256, 0, stream>>>(fullqkv, mask, flags, attn);

    // 4) out = attn @ proj_w + proj_b (float32 out)
    gemm_kernel<1, DD, float>
        <<<dim3(DD / 64, BS * RTOT / 64), 256, 0, stream>>>(
        attn, nullptr, proj_w, proj_b, flags, out);
}

// Round 8
// 611.838 us; speedup vs baseline: 12.6493x; 1.7007x over previous
//
#include <hip/hip_runtime.h>
#include <hip/hip_bf16.h>

#define BS   2
#define PP   512
#define NN   2048
#define DD   768
#define HH   12
#define HD   64
#define RTOT 2560   // P + N rows per batch
#define QKVC 2304   // 3*D

typedef __attribute__((ext_vector_type(8))) short  short8;
typedef __attribute__((ext_vector_type(4))) float  floatx4;

__device__ __forceinline__ float bf2f(unsigned short x) {
    union { unsigned u; float f; } c; c.u = ((unsigned)x) << 16; return c.f;
}
__device__ __forceinline__ unsigned short f2bf(float x) {
    union { float f; unsigned u; } c; c.f = x;
    unsigned r = c.u + 0x7fff + ((c.u >> 16) & 1);   // RNE
    return (unsigned short)(r >> 16);
}

// Runtime-dtype loads (f32 vs bf16). Branch is wave-uniform.
__device__ __forceinline__ float4 load4(const void* p, size_t i, bool f32) {
    if (f32) return *(const float4*)((const float*)p + i);
    ushort4 u = *(const ushort4*)((const unsigned short*)p + i);
    return make_float4(bf2f(u.x), bf2f(u.y), bf2f(u.z), bf2f(u.w));
}
__device__ __forceinline__ float load1(const void* p, size_t i, bool f32) {
    return f32 ? ((const float*)p)[i] : bf2f(((const unsigned short*)p)[i]);
}
// Mask read with runtime type: 0 = int32, 1 = packed u8, 2 = float32
__device__ __forceinline__ bool mask_at(const void* m, int idx, int mtype) {
    if (mtype == 2) return ((const float*)m)[idx] != 0.0f;
    if (mtype == 1) return ((const unsigned char*)m)[idx] != 0;
    return ((const int*)m)[idx] != 0;
}
__device__ __forceinline__ void store_out(float* p, size_t i, float v) { p[i] = v; }
__device__ __forceinline__ void store_out(__hip_bfloat16* p, size_t i, float v) {
    p[i] = __float2bfloat16(v);
}

// ---------------------------------------------------------------------------
// Runtime dtype detection (graph-safe). flags[0]: inputs f32?  flags[1]: mask type
// ---------------------------------------------------------------------------
__global__ void detect_kernel(const void* __restrict__ w,
                              const void* __restrict__ mask,
                              int* __restrict__ flags) {
    __shared__ int s_f32, s_fmask, s_bmask;
    if (threadIdx.x == 0) { s_f32 = 0; s_fmask = 0; s_bmask = 0; }
    __syncthreads();
    const unsigned short* u = (const unsigned short*)w;
    int bad = 0;
    for (int i = threadIdx.x * 2; i < 65536; i += 512) {
        float v = bf2f(u[i]);
        if (!(fabsf(v) <= 2.0f)) bad = 1;
    }
    if (bad) atomicOr(&s_f32, 1);
    const unsigned* mw = (const unsigned*)mask;
    int fm = 0, bm = 0;
    for (int i = threadIdx.x; i < 256; i += 256) {
        unsigned v = mw[i];
        if (v == 0x3F800000u) fm = 1;
        else if ((v & 0xFFFFFF00u) != 0u) bm = 1;
    }
    if (fm) atomicOr(&s_fmask, 1);
    if (bm) atomicOr(&s_bmask, 1);
    __syncthreads();
    if (threadIdx.x == 0) {
        flags[0] = s_f32;
        flags[1] = s_fmask ? 2 : (s_bmask ? 1 : 0);
    }
}

// ---------------------------------------------------------------------------
// 64x64-tile GEMM (unchanged — next round's target).
// ---------------------------------------------------------------------------
template<int MODE, int NCOL, typename OutT>
__global__ __launch_bounds__(256) void gemm_kernel(
    const void* __restrict__ A0, const void* __restrict__ A1,
    const void* __restrict__ W, const void* __restrict__ bias,
    const int* __restrict__ flags, OutT* __restrict__ out)
{
    const bool f32 = flags[0] != 0;
    alignas(16) __shared__ float As[16][68];
    alignas(16) __shared__ float Bsh[16][68];
    const int tid  = threadIdx.x;
    const int row0 = blockIdx.y * 64;
    const int col0 = blockIdx.x * 64;
    const int ty = tid >> 4, tx = tid & 15;
    const int a_row = tid >> 2;
    const int a_k4  = (tid & 3) * 4;
    const int grow  = row0 + a_row;
    const void* abase; size_t aoff; bool af32;
    if (MODE == 0) {
        int b = grow / RTOT, r = grow % RTOT;
        if (r < NN) { abase = A0; aoff = (size_t)(b * NN + r) * DD; }
        else        { abase = A1; aoff = (size_t)(b * PP + (r - NN)) * DD; }
        af32 = f32;
    } else {
        abase = A0; aoff = (size_t)grow * DD; af32 = false;
    }
    const int b_k  = tid >> 4;
    const int b_n4 = (tid & 15) * 4;
    float acc[4][4] = {};
    for (int k0 = 0; k0 < DD; k0 += 16) {
        float4 fa = load4(abase, aoff + k0 + a_k4, af32);
        As[a_k4 + 0][a_row] = fa.x;
        As[a_k4 + 1][a_row] = fa.y;
        As[a_k4 + 2][a_row] = fa.z;
        As[a_k4 + 3][a_row] = fa.w;
        float4 fb = load4(W, (size_t)(k0 + b_k) * NCOL + col0 + b_n4, f32);
        *(float4*)&Bsh[b_k][b_n4] = fb;
        __syncthreads();
        #pragma unroll
        for (int kk = 0; kk < 16; kk++) {
            float4 av = *(const float4*)&As[kk][ty * 4];
            float4 bv = *(const float4*)&Bsh[kk][tx * 4];
            float a_[4] = {av.x, av.y, av.z, av.w};
            float b_[4] = {bv.x, bv.y, bv.z, bv.w};
            #pragma unroll
            for (int i = 0; i < 4; i++)
                #pragma unroll
                for (int j = 0; j < 4; j++)
                    acc[i][j] += a_[i] * b_[j];
        }
        __syncthreads();
    }
    #pragma unroll
    for (int i = 0; i < 4; i++) {
        int gr = row0 + ty * 4 + i;
        #pragma unroll
        for (int j = 0; j < 4; j++) {
            int gc = col0 + tx * 4 + j;
            float v = acc[i][j] + load1(bias, gc, f32);
            if (MODE == 0) {
                store_out(out, (size_t)gr * NCOL + gc, v);
            } else {
                int b = gr / RTOT, r = gr % RTOT;
                size_t dst = (r < PP)
                    ? ((size_t)(b * PP + r) * DD + gc)
                    : ((size_t)BS * PP * DD + (size_t)(b * NN + (r - PP)) * DD + gc);
                store_out(out, dst, v);
            }
        }
    }
}

// ---------------------------------------------------------------------------
// MFMA flash attention (mfma_f32_16x16x32_bf16).
// Block = 256 thr = 4 waves; each wave owns a 16-query strip of a 64-query
// tile for one (b,h). K-tiles of 64 keys staged in LDS: K natural bf16,
// V transposed bf16 (Vt[dv][m]). P round-trips through per-wave LDS strip.
// Layouts (guide m89/m120): A[m=lane&15][k=(lane>>4)*8+j];
// B[k=(lane>>4)*8+j][n=lane&15]; C/D row=(lane>>4)*4+reg, col=lane&15.
// All LDS row strides = 72 elems (144 B, 16B-multiple) for b128 alignment.
// ---------------------------------------------------------------------------
template<int MODE>
__global__ __launch_bounds__(256) void fattn_kernel(
    const __hip_bfloat16* __restrict__ qkv,
    const void* __restrict__ mask,
    const int* __restrict__ flags,
    __hip_bfloat16* __restrict__ attn_out)
{
    constexpr int NQ    = (MODE == 0) ? NN : PP;
    constexpr int NK    = (MODE == 0) ? RTOT : PP;
    constexpr int QOFF  = (MODE == 0) ? PP : 0;
    constexpr int NTILE = NK / 64;

    alignas(16) __shared__ unsigned short Ks[64][72];     // [key m][d]
    alignas(16) __shared__ unsigned short Vt[64][72];     // [dv][key m]
    alignas(16) __shared__ unsigned short Psm[4][16][72]; // per-wave [q][m]

    const int tid   = threadIdx.x;
    const int w     = tid >> 6;        // wave 0..3
    const int lane  = tid & 63;
    const int grp   = lane >> 4;       // 0..3
    const int li    = lane & 15;       // 0..15
    const int nqb   = NQ / 64;
    const int q0    = (blockIdx.x % nqb) * 64;
    const int h     = (blockIdx.x / nqb) % HH;
    const int b     = blockIdx.x / (nqb * HH);
    const int mtype = flags[1];

    const unsigned short* qkv_u = (const unsigned short*)qkv;

    // staging indices
    const int lr  = tid >> 2;          // row 0..63
    const int ld0 = (tid & 3) << 4;    // d offset 0,16,32,48

    // ---- Q A-frags (held in registers for the whole kernel) ----
    short8 qf[2];
    {
        const unsigned short* qp = qkv_u +
            (size_t)(b * RTOT + QOFF + q0 + w * 16 + li) * QKVC + h * HD + grp * 8;
        qf[0] = *(const short8*)(qp);
        qf[1] = *(const short8*)(qp + 32);
    }

    floatx4 o[4] = {{0.f,0.f,0.f,0.f},{0.f,0.f,0.f,0.f},
                    {0.f,0.f,0.f,0.f},{0.f,0.f,0.f,0.f}};
    float mrun[4] = {-3e38f, -3e38f, -3e38f, -3e38f};
    float lrun[4] = {0.f, 0.f, 0.f, 0.f};

    for (int t = 0; t < NTILE; t++) {
        const int m0 = t * 64;
        __syncthreads();   // previous tile's LDS reads complete before overwrite
        // ---- stage K (natural) and V (transposed) ----
        {
            const unsigned short* kp = qkv_u +
                (size_t)(b * RTOT + m0 + lr) * QKVC + DD + h * HD + ld0;
            *(uint4*)&Ks[lr][ld0]     = ((const uint4*)kp)[0];
            *(uint4*)&Ks[lr][ld0 + 8] = ((const uint4*)kp)[1];
            const unsigned short* vp = kp + DD;
            unsigned short tmp[16];
            *(uint4*)&tmp[0] = ((const uint4*)vp)[0];
            *(uint4*)&tmp[8] = ((const uint4*)vp)[1];
            #pragma unroll
            for (int j = 0; j < 16; j++) Vt[ld0 + j][lr] = tmp[j];
        }
        __syncthreads();

        // ---- S = Q K^T : 4 n-tiles x 2 k-steps ----
        floatx4 sf[4];
        #pragma unroll
        for (int n = 0; n < 4; n++) {
            floatx4 acc = {0.f, 0.f, 0.f, 0.f};
            short8 kb0 = *(const short8*)&Ks[n * 16 + li][grp * 8];
            short8 kb1 = *(const short8*)&Ks[n * 16 + li][32 + grp * 8];
            acc = __builtin_amdgcn_mfma_f32_16x16x32_bf16(qf[0], kb0, acc, 0, 0, 0);
            acc = __builtin_amdgcn_mfma_f32_16x16x32_bf16(qf[1], kb1, acc, 0, 0, 0);
            sf[n] = acc;
        }

        // ---- mask bits for this lane's 4 key columns ----
        bool mk[4];
        #pragma unroll
        for (int n = 0; n < 4; n++) {
            int m = m0 + n * 16 + li;
            mk[n] = (m < PP) && mask_at(mask, b * PP + m, mtype);
        }

        // ---- online softmax per D-row (q = grp*4 + r), write P to LDS ----
        #pragma unroll
        for (int r = 0; r < 4; r++) {
            float sv[4];
            #pragma unroll
            for (int n = 0; n < 4; n++)
                sv[n] = mk[n] ? -1e30f : sf[n][r] * 0.125f;
            float tm = fmaxf(fmaxf(sv[0], sv[1]), fmaxf(sv[2], sv[3]));
            #pragma unroll
            for (int off = 1; off < 16; off <<= 1)
                tm = fmaxf(tm, __shfl_xor(tm, off));
            float mnew = fmaxf(mrun[r], tm);
            float al = __expf(mrun[r] - mnew);
            float p[4], ts = 0.f;
            #pragma unroll
            for (int n = 0; n < 4; n++) {
                p[n] = (sv[n] < -1e29f) ? 0.f : __expf(sv[n] - mnew);
                ts += p[n];
            }
            #pragma unroll
            for (int off = 1; off < 16; off <<= 1)
                ts += __shfl_xor(ts, off);
            mrun[r] = mnew;
            lrun[r] = lrun[r] * al + ts;
            #pragma unroll
            for (int n = 0; n < 4; n++) {
                o[n][r] *= al;
                Psm[w][grp * 4 + r][n * 16 + li] = f2bf(p[n]);
            }
        }
        __syncthreads();   // P visible (also orders own-wave LDS w->r)

        // ---- O += P V : 2 m-steps x 4 dv-tiles ----
        #pragma unroll
        for (int s2 = 0; s2 < 2; s2++) {
            short8 pa = *(const short8*)&Psm[w][li][s2 * 32 + grp * 8];
            #pragma unroll
            for (int n2 = 0; n2 < 4; n2++) {
                short8 vf = *(const short8*)&Vt[n2 * 16 + li][s2 * 32 + grp * 8];
                o[n2] = __builtin_amdgcn_mfma_f32_16x16x32_bf16(pa, vf, o[n2], 0, 0, 0);
            }
        }
    }

    // ---- epilogue: D-layout row q = w*16 + grp*4 + r, col dv = n2*16 + li ----
    unsigned short* ao = (unsigned short*)attn_out;
    #pragma unroll
    for (int r = 0; r < 4; r++) {
        float inv = 1.0f / lrun[r];
        int qloc = q0 + w * 16 + grp * 4 + r;
        if (MODE == 0) {
            size_t row = (size_t)(b * RTOT + PP + qloc);
            #pragma unroll
            for (int n2 = 0; n2 < 4; n2++)
                ao[row * DD + h * HD + n2 * 16 + li] = f2bf(o[n2][r] * inv);
        } else {
            #pragma unroll
            for (int n2 = 0; n2 < 4; n2++) {
                int dc = n2 * 16 + li;
                int f = h * (HD * PP) + dc * PP + qloc;
                ao[(size_t)(b * RTOT + f / DD) * DD + (f % DD)] = f2bf(o[n2][r] * inv);
            }
        }
    }
}

// ---------------------------------------------------------------------------
extern "C" void kernel_launch(void* const* d_in, const int* in_sizes, int n_in,
                              void* d_out, int out_size, void* d_ws, size_t ws_size,
                              hipStream_t stream) {
    const void *xs = nullptr, *xq = nullptr, *mask = nullptr,
               *qkv_w = nullptr, *qkv_b = nullptr, *proj_w = nullptr, *proj_b = nullptr;
    for (int i = 0; i < n_in; i++) {
        switch (in_sizes[i]) {
            case BS * PP * DD:   xs     = d_in[i]; break;
            case BS * NN * DD:   xq     = d_in[i]; break;
            case BS * PP:        mask   = d_in[i]; break;
            case DD * QKVC:      qkv_w  = d_in[i]; break;
            case QKVC:           qkv_b  = d_in[i]; break;
            case DD * DD:        proj_w = d_in[i]; break;
            case DD:             proj_b = d_in[i]; break;
        }
    }
    if (!xs || !xq || !mask || !qkv_w || !qkv_b || !proj_w || !proj_b) {
        xs = d_in[0]; xq = d_in[1]; mask = d_in[2];
        qkv_w = d_in[3]; qkv_b = d_in[4]; proj_w = d_in[5]; proj_b = d_in[6];
    }

    float* out = (float*)d_out;   // reference output dtype is float32

    int* flags = (int*)d_ws;
    __hip_bfloat16* fullqkv = (__hip_bfloat16*)((char*)d_ws + 256); // [BS*2560, 2304]
    __hip_bfloat16* attn    = fullqkv + (size_t)BS * RTOT * QKVC;   // [BS*2560, 768]

    detect_kernel<<<1, 256, 0, stream>>>(qkv_w, mask, flags);

    // 1) fullqkv = concat([xq, xs]) @ qkv_w + qkv_b
    gemm_kernel<0, QKVC, __hip_bfloat16>
        <<<dim3(QKVC / 64, BS * RTOT / 64), 256, 0, stream>>>(
        xq, xs, qkv_w, qkv_b, flags, fullqkv);

    // 2) cross attention (MFMA flash) -> attn rows 512..2559
    fattn_kernel<0><<<BS * HH * (NN / 64), 256, 0, stream>>>(fullqkv, mask, flags, attn);

    // 3) self attention (MFMA flash, scrambled) -> attn rows 0..511
    fattn_kernel<1><<<BS * HH * (PP / 64), 256, 0, stream>>>(fullqkv, mask, flags, attn);

    // 4) out = attn @ proj_w + proj_b (float32 out)
    gemm_kernel<1, DD, float>
        <<<dim3(DD / 64, BS * RTOT / 64), 256, 0, stream>>>(
        attn, nullptr, proj_w, proj_b, flags, out);
}

// Round 9
// 340.904 us; speedup vs baseline: 22.7023x; 1.7948x over previous
//
#include <hip/hip_runtime.h>
#include <hip/hip_bf16.h>

#define BS   2
#define PP   512
#define NN   2048
#define DD   768
#define HH   12
#define HD   64
#define RTOT 2560   // P + N rows per batch
#define QKVC 2304   // 3*D
#define MTOT (BS * RTOT)   // 5120

typedef __attribute__((ext_vector_type(8))) short  short8;
typedef __attribute__((ext_vector_type(4))) float  floatx4;

__device__ __forceinline__ float bf2f(unsigned short x) {
    union { unsigned u; float f; } c; c.u = ((unsigned)x) << 16; return c.f;
}
__device__ __forceinline__ unsigned short f2bf(float x) {
    union { float f; unsigned u; } c; c.f = x;
    unsigned r = c.u + 0x7fff + ((c.u >> 16) & 1);   // RNE
    return (unsigned short)(r >> 16);
}

// Runtime-dtype loads (f32 vs bf16). Branch is wave-uniform.
__device__ __forceinline__ float4 load4(const void* p, size_t i, bool f32) {
    if (f32) return *(const float4*)((const float*)p + i);
    ushort4 u = *(const ushort4*)((const unsigned short*)p + i);
    return make_float4(bf2f(u.x), bf2f(u.y), bf2f(u.z), bf2f(u.w));
}
__device__ __forceinline__ float load1(const void* p, size_t i, bool f32) {
    return f32 ? ((const float*)p)[i] : bf2f(((const unsigned short*)p)[i]);
}
// Mask read with runtime type: 0 = int32, 1 = packed u8, 2 = float32
__device__ __forceinline__ bool mask_at(const void* m, int idx, int mtype) {
    if (mtype == 2) return ((const float*)m)[idx] != 0.0f;
    if (mtype == 1) return ((const unsigned char*)m)[idx] != 0;
    return ((const int*)m)[idx] != 0;
}
__device__ __forceinline__ void store_out(float* p, size_t i, float v) { p[i] = v; }
__device__ __forceinline__ void store_out(__hip_bfloat16* p, size_t i, float v) {
    p[i] = __float2bfloat16(v);
}

// ---------------------------------------------------------------------------
// Runtime dtype detection (graph-safe). flags[0]: inputs f32?  flags[1]: mask type
// ---------------------------------------------------------------------------
__global__ void detect_kernel(const void* __restrict__ w,
                              const void* __restrict__ mask,
                              int* __restrict__ flags) {
    __shared__ int s_f32, s_fmask, s_bmask;
    if (threadIdx.x == 0) { s_f32 = 0; s_fmask = 0; s_bmask = 0; }
    __syncthreads();
    const unsigned short* u = (const unsigned short*)w;
    int bad = 0;
    for (int i = threadIdx.x * 2; i < 65536; i += 512) {
        float v = bf2f(u[i]);
        if (!(fabsf(v) <= 2.0f)) bad = 1;
    }
    if (bad) atomicOr(&s_f32, 1);
    const unsigned* mw = (const unsigned*)mask;
    int fm = 0, bm = 0;
    for (int i = threadIdx.x; i < 256; i += 256) {
        unsigned v = mw[i];
        if (v == 0x3F800000u) fm = 1;
        else if ((v & 0xFFFFFF00u) != 0u) bm = 1;
    }
    if (fm) atomicOr(&s_fmask, 1);
    if (bm) atomicOr(&s_bmask, 1);
    __syncthreads();
    if (threadIdx.x == 0) {
        flags[0] = s_f32;
        flags[1] = s_fmask ? 2 : (s_bmask ? 1 : 0);
    }
}

// ---------------------------------------------------------------------------
// Prep 1: Abf[5120][768] bf16 = concat([xq, xs]) per batch, runtime dtype in.
// Grid: 5120 blocks x 192 threads; each thread converts 4 elements.
// ---------------------------------------------------------------------------
__global__ __launch_bounds__(192) void concat_convert_kernel(
    const void* __restrict__ xq, const void* __restrict__ xs,
    const int* __restrict__ flags, unsigned short* __restrict__ Abf)
{
    const bool f32 = flags[0] != 0;
    const int r = blockIdx.x;
    const int b = r / RTOT, rr = r % RTOT;
    const void* src;
    size_t off;
    if (rr < NN) { src = xq; off = (size_t)(b * NN + rr) * DD; }
    else         { src = xs; off = (size_t)(b * PP + (rr - NN)) * DD; }
    const int t = threadIdx.x;
    float4 v = load4(src, off + t * 4, f32);
    ushort4 o;
    o.x = f2bf(v.x); o.y = f2bf(v.y); o.z = f2bf(v.z); o.w = f2bf(v.w);
    *(ushort4*)&Abf[(size_t)r * DD + t * 4] = o;
}

// ---------------------------------------------------------------------------
// Prep 2: out[C][R] bf16 = transpose(in[R][C]), runtime dtype in.
// Grid: (C/64, R/64), 256 threads. LDS tile transpose, coalesced both sides.
// ---------------------------------------------------------------------------
__global__ __launch_bounds__(256) void transpose_kernel(
    const void* __restrict__ in, int R, int C,
    const int* __restrict__ flags, unsigned short* __restrict__ out)
{
    const bool f32 = flags[0] != 0;
    __shared__ unsigned short T[64][65];
    const int c0 = blockIdx.x * 64, r0 = blockIdx.y * 64;
    const int col = threadIdx.x & 63;
    const int r4  = threadIdx.x >> 6;
    #pragma unroll
    for (int p = 0; p < 16; p++) {
        int row = p * 4 + r4;
        T[row][col] = f2bf(load1(in, (size_t)(r0 + row) * C + c0 + col, f32));
    }
    __syncthreads();
    #pragma unroll
    for (int p = 0; p < 16; p++) {
        int crow = p * 4 + r4;
        out[(size_t)(c0 + crow) * R + r0 + col] = T[col][crow];
    }
}

// ---------------------------------------------------------------------------
// MFMA GEMM: C[M][NCOL] = A[M][768] @ BT[NCOL][768]^T + bias.
// 128x128 tile, 4 waves each 64x64, BK=64, mfma_f32_16x16x32_bf16.
// Fragment layouts as verified in fattn: A[m=li][k=grp*8+j] contiguous short8;
// B from BT row n, k contiguous; C/D row=grp*4+r, col=li.
// MODE 0: out bf16 natural (fullqkv). MODE 1: out f32 with split row mapping.
// ---------------------------------------------------------------------------
template<int MODE, int NCOL>
__global__ __launch_bounds__(256) void mgemm_kernel(
    const unsigned short* __restrict__ A,    // [M][768] bf16
    const unsigned short* __restrict__ BT,   // [NCOL][768] bf16
    const void* __restrict__ bias,           // [NCOL] runtime dtype
    const int* __restrict__ flags,
    void* __restrict__ outp)
{
    alignas(16) __shared__ unsigned short Ash[128][72];
    alignas(16) __shared__ unsigned short Bsh[128][72];

    const int tid  = threadIdx.x;
    const int w    = tid >> 6;
    const int lane = tid & 63;
    const int grp  = lane >> 4;
    const int li   = lane & 15;
    const int row0 = blockIdx.y * 128;
    const int col0 = blockIdx.x * 128;
    const int moff = (w >> 1) * 64;
    const int noff = (w & 1) * 64;

    const int srow = tid >> 1;         // staging row 0..127
    const int sseg = (tid & 1) * 32;   // k-half 0 / 32

    floatx4 o[4][4];
    #pragma unroll
    for (int i = 0; i < 4; i++)
        #pragma unroll
        for (int j = 0; j < 4; j++)
            o[i][j] = (floatx4){0.f, 0.f, 0.f, 0.f};

    for (int k0 = 0; k0 < DD; k0 += 64) {
        // ---- global loads (bf16, contiguous 64B per thread) ----
        const uint4* ap = (const uint4*)(A  + (size_t)(row0 + srow) * DD + k0 + sseg);
        const uint4* bp = (const uint4*)(BT + (size_t)(col0 + srow) * DD + k0 + sseg);
        uint4 a0 = ap[0], a1 = ap[1], a2 = ap[2], a3 = ap[3];
        uint4 b0 = bp[0], b1 = bp[1], b2 = bp[2], b3 = bp[3];
        __syncthreads();   // previous iter's LDS reads complete
        *(uint4*)&Ash[srow][sseg +  0] = a0;
        *(uint4*)&Ash[srow][sseg +  8] = a1;
        *(uint4*)&Ash[srow][sseg + 16] = a2;
        *(uint4*)&Ash[srow][sseg + 24] = a3;
        *(uint4*)&Bsh[srow][sseg +  0] = b0;
        *(uint4*)&Bsh[srow][sseg +  8] = b1;
        *(uint4*)&Bsh[srow][sseg + 16] = b2;
        *(uint4*)&Bsh[srow][sseg + 24] = b3;
        __syncthreads();

        // ---- compute: 2 k-steps x 4x4 tiles ----
        #pragma unroll
        for (int ks = 0; ks < 2; ks++) {
            short8 af[4], bf[4];
            #pragma unroll
            for (int i = 0; i < 4; i++)
                af[i] = *(const short8*)&Ash[moff + i * 16 + li][ks * 32 + grp * 8];
            #pragma unroll
            for (int j = 0; j < 4; j++)
                bf[j] = *(const short8*)&Bsh[noff + j * 16 + li][ks * 32 + grp * 8];
            #pragma unroll
            for (int i = 0; i < 4; i++)
                #pragma unroll
                for (int j = 0; j < 4; j++)
                    o[i][j] = __builtin_amdgcn_mfma_f32_16x16x32_bf16(
                        af[i], bf[j], o[i][j], 0, 0, 0);
        }
    }

    // ---- epilogue ----
    const bool f32 = flags[0] != 0;
    float bv[4];
    #pragma unroll
    for (int j = 0; j < 4; j++)
        bv[j] = load1(bias, col0 + noff + j * 16 + li, f32);

    #pragma unroll
    for (int i = 0; i < 4; i++) {
        #pragma unroll
        for (int r = 0; r < 4; r++) {
            int grow = row0 + moff + i * 16 + grp * 4 + r;
            #pragma unroll
            for (int j = 0; j < 4; j++) {
                int gcol = col0 + noff + j * 16 + li;
                float v = o[i][j][r] + bv[j];
                if (MODE == 0) {
                    ((unsigned short*)outp)[(size_t)grow * NCOL + gcol] = f2bf(v);
                } else {
                    int b = grow / RTOT, rr = grow % RTOT;
                    size_t dst = (rr < PP)
                        ? ((size_t)(b * PP + rr) * DD + gcol)
                        : ((size_t)BS * PP * DD + (size_t)(b * NN + (rr - PP)) * DD + gcol);
                    ((float*)outp)[dst] = v;
                }
            }
        }
    }
}

// ---------------------------------------------------------------------------
// Fallback f32-vector GEMM (round-8 path, used only if ws too small).
// ---------------------------------------------------------------------------
template<int MODE, int NCOL, typename OutT>
__global__ __launch_bounds__(256) void gemm_kernel(
    const void* __restrict__ A0, const void* __restrict__ A1,
    const void* __restrict__ W, const void* __restrict__ bias,
    const int* __restrict__ flags, OutT* __restrict__ out)
{
    const bool f32 = flags[0] != 0;
    alignas(16) __shared__ float As[16][68];
    alignas(16) __shared__ float Bsh2[16][68];
    const int tid  = threadIdx.x;
    const int row0 = blockIdx.y * 64;
    const int col0 = blockIdx.x * 64;
    const int ty = tid >> 4, tx = tid & 15;
    const int a_row = tid >> 2;
    const int a_k4  = (tid & 3) * 4;
    const int grow  = row0 + a_row;
    const void* abase; size_t aoff; bool af32;
    if (MODE == 0) {
        int b = grow / RTOT, r = grow % RTOT;
        if (r < NN) { abase = A0; aoff = (size_t)(b * NN + r) * DD; }
        else        { abase = A1; aoff = (size_t)(b * PP + (r - NN)) * DD; }
        af32 = f32;
    } else {
        abase = A0; aoff = (size_t)grow * DD; af32 = false;
    }
    const int b_k  = tid >> 4;
    const int b_n4 = (tid & 15) * 4;
    float acc[4][4] = {};
    for (int k0 = 0; k0 < DD; k0 += 16) {
        float4 fa = load4(abase, aoff + k0 + a_k4, af32);
        As[a_k4 + 0][a_row] = fa.x;
        As[a_k4 + 1][a_row] = fa.y;
        As[a_k4 + 2][a_row] = fa.z;
        As[a_k4 + 3][a_row] = fa.w;
        float4 fb = load4(W, (size_t)(k0 + b_k) * NCOL + col0 + b_n4, f32);
        *(float4*)&Bsh2[b_k][b_n4] = fb;
        __syncthreads();
        #pragma unroll
        for (int kk = 0; kk < 16; kk++) {
            float4 av = *(const float4*)&As[kk][ty * 4];
            float4 bvv = *(const float4*)&Bsh2[kk][tx * 4];
            float a_[4] = {av.x, av.y, av.z, av.w};
            float b_[4] = {bvv.x, bvv.y, bvv.z, bvv.w};
            #pragma unroll
            for (int i = 0; i < 4; i++)
                #pragma unroll
                for (int j = 0; j < 4; j++)
                    acc[i][j] += a_[i] * b_[j];
        }
        __syncthreads();
    }
    #pragma unroll
    for (int i = 0; i < 4; i++) {
        int gr = row0 + ty * 4 + i;
        #pragma unroll
        for (int j = 0; j < 4; j++) {
            int gc = col0 + tx * 4 + j;
            float v = acc[i][j] + load1(bias, gc, f32);
            if (MODE == 0) {
                store_out(out, (size_t)gr * NCOL + gc, v);
            } else {
                int b = gr / RTOT, r = gr % RTOT;
                size_t dst = (r < PP)
                    ? ((size_t)(b * PP + r) * DD + gc)
                    : ((size_t)BS * PP * DD + (size_t)(b * NN + (r - PP)) * DD + gc);
                store_out(out, dst, v);
            }
        }
    }
}

// ---------------------------------------------------------------------------
// MFMA flash attention (unchanged from passing round 8).
// ---------------------------------------------------------------------------
template<int MODE>
__global__ __launch_bounds__(256) void fattn_kernel(
    const __hip_bfloat16* __restrict__ qkv,
    const void* __restrict__ mask,
    const int* __restrict__ flags,
    __hip_bfloat16* __restrict__ attn_out)
{
    constexpr int NQ    = (MODE == 0) ? NN : PP;
    constexpr int NK    = (MODE == 0) ? RTOT : PP;
    constexpr int QOFF  = (MODE == 0) ? PP : 0;
    constexpr int NTILE = NK / 64;

    alignas(16) __shared__ unsigned short Ks[64][72];     // [key m][d]
    alignas(16) __shared__ unsigned short Vt[64][72];     // [dv][key m]
    alignas(16) __shared__ unsigned short Psm[4][16][72]; // per-wave [q][m]

    const int tid   = threadIdx.x;
    const int w     = tid >> 6;
    const int lane  = tid & 63;
    const int grp   = lane >> 4;
    const int li    = lane & 15;
    const int nqb   = NQ / 64;
    const int q0    = (blockIdx.x % nqb) * 64;
    const int h     = (blockIdx.x / nqb) % HH;
    const int b     = blockIdx.x / (nqb * HH);
    const int mtype = flags[1];

    const unsigned short* qkv_u = (const unsigned short*)qkv;
    const int lr  = tid >> 2;
    const int ld0 = (tid & 3) << 4;

    short8 qf[2];
    {
        const unsigned short* qp = qkv_u +
            (size_t)(b * RTOT + QOFF + q0 + w * 16 + li) * QKVC + h * HD + grp * 8;
        qf[0] = *(const short8*)(qp);
        qf[1] = *(const short8*)(qp + 32);
    }

    floatx4 o[4] = {{0.f,0.f,0.f,0.f},{0.f,0.f,0.f,0.f},
                    {0.f,0.f,0.f,0.f},{0.f,0.f,0.f,0.f}};
    float mrun[4] = {-3e38f, -3e38f, -3e38f, -3e38f};
    float lrun[4] = {0.f, 0.f, 0.f, 0.f};

    for (int t = 0; t < NTILE; t++) {
        const int m0 = t * 64;
        __syncthreads();
        {
            const unsigned short* kp = qkv_u +
                (size_t)(b * RTOT + m0 + lr) * QKVC + DD + h * HD + ld0;
            *(uint4*)&Ks[lr][ld0]     = ((const uint4*)kp)[0];
            *(uint4*)&Ks[lr][ld0 + 8] = ((const uint4*)kp)[1];
            const unsigned short* vp = kp + DD;
            unsigned short tmp[16];
            *(uint4*)&tmp[0] = ((const uint4*)vp)[0];
            *(uint4*)&tmp[8] = ((const uint4*)vp)[1];
            #pragma unroll
            for (int j = 0; j < 16; j++) Vt[ld0 + j][lr] = tmp[j];
        }
        __syncthreads();

        floatx4 sf[4];
        #pragma unroll
        for (int n = 0; n < 4; n++) {
            floatx4 acc = {0.f, 0.f, 0.f, 0.f};
            short8 kb0 = *(const short8*)&Ks[n * 16 + li][grp * 8];
            short8 kb1 = *(const short8*)&Ks[n * 16 + li][32 + grp * 8];
            acc = __builtin_amdgcn_mfma_f32_16x16x32_bf16(qf[0], kb0, acc, 0, 0, 0);
            acc = __builtin_amdgcn_mfma_f32_16x16x32_bf16(qf[1], kb1, acc, 0, 0, 0);
            sf[n] = acc;
        }

        bool mk[4];
        #pragma unroll
        for (int n = 0; n < 4; n++) {
            int m = m0 + n * 16 + li;
            mk[n] = (m < PP) && mask_at(mask, b * PP + m, mtype);
        }

        #pragma unroll
        for (int r = 0; r < 4; r++) {
            float sv[4];
            #pragma unroll
            for (int n = 0; n < 4; n++)
                sv[n] = mk[n] ? -1e30f : sf[n][r] * 0.125f;
            float tm = fmaxf(fmaxf(sv[0], sv[1]), fmaxf(sv[2], sv[3]));
            #pragma unroll
            for (int off = 1; off < 16; off <<= 1)
                tm = fmaxf(tm, __shfl_xor(tm, off));
            float mnew = fmaxf(mrun[r], tm);
            float al = __expf(mrun[r] - mnew);
            float p[4], ts = 0.f;
            #pragma unroll
            for (int n = 0; n < 4; n++) {
                p[n] = (sv[n] < -1e29f) ? 0.f : __expf(sv[n] - mnew);
                ts += p[n];
            }
            #pragma unroll
            for (int off = 1; off < 16; off <<= 1)
                ts += __shfl_xor(ts, off);
            mrun[r] = mnew;
            lrun[r] = lrun[r] * al + ts;
            #pragma unroll
            for (int n = 0; n < 4; n++) {
                o[n][r] *= al;
                Psm[w][grp * 4 + r][n * 16 + li] = f2bf(p[n]);
            }
        }
        __syncthreads();

        #pragma unroll
        for (int s2 = 0; s2 < 2; s2++) {
            short8 pa = *(const short8*)&Psm[w][li][s2 * 32 + grp * 8];
            #pragma unroll
            for (int n2 = 0; n2 < 4; n2++) {
                short8 vf = *(const short8*)&Vt[n2 * 16 + li][s2 * 32 + grp * 8];
                o[n2] = __builtin_amdgcn_mfma_f32_16x16x32_bf16(pa, vf, o[n2], 0, 0, 0);
            }
        }
    }

    unsigned short* ao = (unsigned short*)attn_out;
    #pragma unroll
    for (int r = 0; r < 4; r++) {
        float inv = 1.0f / lrun[r];
        int qloc = q0 + w * 16 + grp * 4 + r;
        if (MODE == 0) {
            size_t row = (size_t)(b * RTOT + PP + qloc);
            #pragma unroll
            for (int n2 = 0; n2 < 4; n2++)
                ao[row * DD + h * HD + n2 * 16 + li] = f2bf(o[n2][r] * inv);
        } else {
            #pragma unroll
            for (int n2 = 0; n2 < 4; n2++) {
                int dc = n2 * 16 + li;
                int f = h * (HD * PP) + dc * PP + qloc;
                ao[(size_t)(b * RTOT + f / DD) * DD + (f % DD)] = f2bf(o[n2][r] * inv);
            }
        }
    }
}

// ---------------------------------------------------------------------------
extern "C" void kernel_launch(void* const* d_in, const int* in_sizes, int n_in,
                              void* d_out, int out_size, void* d_ws, size_t ws_size,
                              hipStream_t stream) {
    const void *xs = nullptr, *xq = nullptr, *mask = nullptr,
               *qkv_w = nullptr, *qkv_b = nullptr, *proj_w = nullptr, *proj_b = nullptr;
    for (int i = 0; i < n_in; i++) {
        switch (in_sizes[i]) {
            case BS * PP * DD:   xs     = d_in[i]; break;
            case BS * NN * DD:   xq     = d_in[i]; break;
            case BS * PP:        mask   = d_in[i]; break;
            case DD * QKVC:      qkv_w  = d_in[i]; break;
            case QKVC:           qkv_b  = d_in[i]; break;
            case DD * DD:        proj_w = d_in[i]; break;
            case DD:             proj_b = d_in[i]; break;
        }
    }
    if (!xs || !xq || !mask || !qkv_w || !qkv_b || !proj_w || !proj_b) {
        xs = d_in[0]; xq = d_in[1]; mask = d_in[2];
        qkv_w = d_in[3]; qkv_b = d_in[4]; proj_w = d_in[5]; proj_b = d_in[6];
    }

    float* out = (float*)d_out;   // reference output dtype is float32

    // ws layout (MFMA path):
    //   [0,256)                      flags
    //   fullqkv  bf16 [5120][2304]   23,592,960 B
    //   AB       bf16 [5120][768]     7,864,320 B  (Abf for stage1 / attn later)
    //   WqkvT    bf16 [2304][768]     3,538,944 B
    //   WprojT   bf16 [768][768]      1,179,648 B
    const size_t off_full = 256;
    const size_t off_ab   = off_full + (size_t)MTOT * QKVC * 2;
    const size_t off_wq   = off_ab   + (size_t)MTOT * DD * 2;
    const size_t off_wp   = off_wq   + (size_t)QKVC * DD * 2;
    const size_t need     = off_wp   + (size_t)DD * DD * 2;

    int* flags = (int*)d_ws;
    __hip_bfloat16* fullqkv = (__hip_bfloat16*)((char*)d_ws + off_full);
    __hip_bfloat16* attn    = (__hip_bfloat16*)((char*)d_ws + off_ab);

    detect_kernel<<<1, 256, 0, stream>>>(qkv_w, mask, flags);

    if (ws_size >= need) {
        unsigned short* Abf    = (unsigned short*)((char*)d_ws + off_ab);
        unsigned short* WqkvT  = (unsigned short*)((char*)d_ws + off_wq);
        unsigned short* WprojT = (unsigned short*)((char*)d_ws + off_wp);

        // prep: concat+convert A, transpose weights to bf16 B^T
        concat_convert_kernel<<<MTOT, 192, 0, stream>>>(xq, xs, flags, Abf);
        transpose_kernel<<<dim3(QKVC / 64, DD / 64), 256, 0, stream>>>(
            qkv_w, DD, QKVC, flags, WqkvT);
        transpose_kernel<<<dim3(DD / 64, DD / 64), 256, 0, stream>>>(
            proj_w, DD, DD, flags, WprojT);

        // 1) fullqkv = Abf @ WqkvT^T + qkv_b   (MFMA)
        mgemm_kernel<0, QKVC><<<dim3(QKVC / 128, MTOT / 128), 256, 0, stream>>>(
            Abf, WqkvT, qkv_b, flags, (void*)fullqkv);

        // 2-3) attention (overwrites AB region with attn)
        fattn_kernel<0><<<BS * HH * (NN / 64), 256, 0, stream>>>(fullqkv, mask, flags, attn);
        fattn_kernel<1><<<BS * HH * (PP / 64), 256, 0, stream>>>(fullqkv, mask, flags, attn);

        // 4) out = attn @ WprojT^T + proj_b  (MFMA, f32 split store)
        mgemm_kernel<1, DD><<<dim3(DD / 128, MTOT / 128), 256, 0, stream>>>(
            (const unsigned short*)attn, WprojT, proj_b, flags, (void*)out);
    } else {
        // fallback: round-8 proven path
        gemm_kernel<0, QKVC, __hip_bfloat16>
            <<<dim3(QKVC / 64, MTOT / 64), 256, 0, stream>>>(
            xq, xs, qkv_w, qkv_b, flags, fullqkv);
        fattn_kernel<0><<<BS * HH * (NN / 64), 256, 0, stream>>>(fullqkv, mask, flags, attn);
        fattn_kernel<1><<<BS * HH * (PP / 64), 256, 0, stream>>>(fullqkv, mask, flags, attn);
        gemm_kernel<1, DD, float>
            <<<dim3(DD / 64, MTOT / 64), 256, 0, stream>>>(
            attn, nullptr, proj_w, proj_b, flags, out);
    }
}

// Round 10
// 307.911 us; speedup vs baseline: 25.1349x; 1.1071x over previous
//
#include <hip/hip_runtime.h>
#include <hip/hip_bf16.h>

#define BS   2
#define PP   512
#define NN   2048
#define DD   768
#define HH   12
#define HD   64
#define RTOT 2560   // P + N rows per batch
#define QKVC 2304   // 3*D
#define MTOT (BS * RTOT)       // 5120
#define CROWS (BS * HH * NN)   // 49152 cross q-rows
#define SROWS (BS * HH * PP)   // 12288 self q-rows
#define TROWS (CROWS + SROWS)  // 61440

typedef __attribute__((ext_vector_type(8))) short  short8;
typedef __attribute__((ext_vector_type(4))) float  floatx4;

__device__ __forceinline__ float bf2f(unsigned short x) {
    union { unsigned u; float f; } c; c.u = ((unsigned)x) << 16; return c.f;
}
__device__ __forceinline__ unsigned short f2bf(float x) {
    union { float f; unsigned u; } c; c.f = x;
    unsigned r = c.u + 0x7fff + ((c.u >> 16) & 1);   // RNE
    return (unsigned short)(r >> 16);
}

__device__ __forceinline__ float4 load4(const void* p, size_t i, bool f32) {
    if (f32) return *(const float4*)((const float*)p + i);
    ushort4 u = *(const ushort4*)((const unsigned short*)p + i);
    return make_float4(bf2f(u.x), bf2f(u.y), bf2f(u.z), bf2f(u.w));
}
__device__ __forceinline__ float load1(const void* p, size_t i, bool f32) {
    return f32 ? ((const float*)p)[i] : bf2f(((const unsigned short*)p)[i]);
}
__device__ __forceinline__ bool mask_at(const void* m, int idx, int mtype) {
    if (mtype == 2) return ((const float*)m)[idx] != 0.0f;
    if (mtype == 1) return ((const unsigned char*)m)[idx] != 0;
    return ((const int*)m)[idx] != 0;
}
__device__ __forceinline__ void store_out(float* p, size_t i, float v) { p[i] = v; }
__device__ __forceinline__ void store_out(__hip_bfloat16* p, size_t i, float v) {
    p[i] = __float2bfloat16(v);
}

// ---------------------------------------------------------------------------
// Runtime dtype detection. flags[0]: inputs f32?  flags[1]: mask type
// ---------------------------------------------------------------------------
__global__ void detect_kernel(const void* __restrict__ w,
                              const void* __restrict__ mask,
                              int* __restrict__ flags) {
    __shared__ int s_f32, s_fmask, s_bmask;
    if (threadIdx.x == 0) { s_f32 = 0; s_fmask = 0; s_bmask = 0; }
    __syncthreads();
    const unsigned short* u = (const unsigned short*)w;
    int bad = 0;
    for (int i = threadIdx.x * 2; i < 65536; i += 512) {
        float v = bf2f(u[i]);
        if (!(fabsf(v) <= 2.0f)) bad = 1;
    }
    if (bad) atomicOr(&s_f32, 1);
    const unsigned* mw = (const unsigned*)mask;
    int fm = 0, bm = 0;
    for (int i = threadIdx.x; i < 256; i += 256) {
        unsigned v = mw[i];
        if (v == 0x3F800000u) fm = 1;
        else if ((v & 0xFFFFFF00u) != 0u) bm = 1;
    }
    if (fm) atomicOr(&s_fmask, 1);
    if (bm) atomicOr(&s_bmask, 1);
    __syncthreads();
    if (threadIdx.x == 0) {
        flags[0] = s_f32;
        flags[1] = s_fmask ? 2 : (s_bmask ? 1 : 0);
    }
}

// ---------------------------------------------------------------------------
// Prep: mask -> additive bias row mb[b*RTOT + m] = -1e30 (masked) / 0.
// ---------------------------------------------------------------------------
__global__ __launch_bounds__(256) void maskbias_kernel(
    const void* __restrict__ mask, const int* __restrict__ flags,
    float* __restrict__ mb)
{
    const int mtype = flags[1];
    for (int i = threadIdx.x; i < BS * RTOT; i += 256) {
        int b = i / RTOT, m = i % RTOT;
        float v = 0.f;
        if (m < PP && mask_at(mask, b * PP + m, mtype)) v = -1e30f;
        mb[i] = v;
    }
}

// ---------------------------------------------------------------------------
// Prep: Abf[5120][768] bf16 = concat([xq, xs]) per batch.
// ---------------------------------------------------------------------------
__global__ __launch_bounds__(192) void concat_convert_kernel(
    const void* __restrict__ xq, const void* __restrict__ xs,
    const int* __restrict__ flags, unsigned short* __restrict__ Abf)
{
    const bool f32 = flags[0] != 0;
    const int r = blockIdx.x;
    const int b = r / RTOT, rr = r % RTOT;
    const void* src;
    size_t off;
    if (rr < NN) { src = xq; off = (size_t)(b * NN + rr) * DD; }
    else         { src = xs; off = (size_t)(b * PP + (rr - NN)) * DD; }
    const int t = threadIdx.x;
    float4 v = load4(src, off + t * 4, f32);
    ushort4 o;
    o.x = f2bf(v.x); o.y = f2bf(v.y); o.z = f2bf(v.z); o.w = f2bf(v.w);
    *(ushort4*)&Abf[(size_t)r * DD + t * 4] = o;
}

// ---------------------------------------------------------------------------
// Prep: out[C][R] bf16 = transpose(in[R][C]).
// ---------------------------------------------------------------------------
__global__ __launch_bounds__(256) void transpose_kernel(
    const void* __restrict__ in, int R, int C,
    const int* __restrict__ flags, unsigned short* __restrict__ out)
{
    const bool f32 = flags[0] != 0;
    __shared__ unsigned short T[64][65];
    const int c0 = blockIdx.x * 64, r0 = blockIdx.y * 64;
    const int col = threadIdx.x & 63;
    const int r4  = threadIdx.x >> 6;
    #pragma unroll
    for (int p = 0; p < 16; p++) {
        int row = p * 4 + r4;
        T[row][col] = f2bf(load1(in, (size_t)(r0 + row) * C + c0 + col, f32));
    }
    __syncthreads();
    #pragma unroll
    for (int p = 0; p < 16; p++) {
        int crow = p * 4 + r4;
        out[(size_t)(c0 + crow) * R + r0 + col] = T[col][crow];
    }
}

// ---------------------------------------------------------------------------
// Prep: VtG[(b*HH+h)][dv][m] bf16 = V^T per head, from fullqkv V block.
// Grid (RTOT/64, BS*HH). One 64x64 tile transpose per block.
// ---------------------------------------------------------------------------
__global__ __launch_bounds__(256) void vtprep_kernel(
    const unsigned short* __restrict__ qkv, unsigned short* __restrict__ VtG)
{
    alignas(16) __shared__ unsigned short T[64][72];
    const int mt = blockIdx.x * 64;
    const int bh = blockIdx.y;
    const int b = bh / HH, h = bh % HH;
    const int lr  = threadIdx.x >> 2;
    const int ld0 = (threadIdx.x & 3) << 4;
    const unsigned short* vp = qkv +
        (size_t)(b * RTOT + mt + lr) * QKVC + 2 * DD + h * HD + ld0;
    *(uint4*)&T[lr][ld0]     = ((const uint4*)vp)[0];
    *(uint4*)&T[lr][ld0 + 8] = ((const uint4*)vp)[1];
    __syncthreads();
    unsigned short tmp[16];
    #pragma unroll
    for (int j = 0; j < 16; j++) tmp[j] = T[ld0 + j][lr];
    unsigned short* dst = VtG + ((size_t)bh * HD + lr) * RTOT + mt + ld0;
    *(uint4*)dst       = *(uint4*)&tmp[0];
    *(uint4*)(dst + 8) = *(uint4*)&tmp[8];
}

// ---------------------------------------------------------------------------
// MFMA GEMM (unchanged from round 9): C[M][NCOL] = A @ BT^T + bias.
// ---------------------------------------------------------------------------
template<int MODE, int NCOL>
__global__ __launch_bounds__(256) void mgemm_kernel(
    const unsigned short* __restrict__ A,
    const unsigned short* __restrict__ BT,
    const void* __restrict__ bias,
    const int* __restrict__ flags,
    void* __restrict__ outp)
{
    alignas(16) __shared__ unsigned short Ash[128][72];
    alignas(16) __shared__ unsigned short Bsh[128][72];

    const int tid  = threadIdx.x;
    const int w    = tid >> 6;
    const int lane = tid & 63;
    const int grp  = lane >> 4;
    const int li   = lane & 15;
    const int row0 = blockIdx.y * 128;
    const int col0 = blockIdx.x * 128;
    const int moff = (w >> 1) * 64;
    const int noff = (w & 1) * 64;
    const int srow = tid >> 1;
    const int sseg = (tid & 1) * 32;

    floatx4 o[4][4];
    #pragma unroll
    for (int i = 0; i < 4; i++)
        #pragma unroll
        for (int j = 0; j < 4; j++)
            o[i][j] = (floatx4){0.f, 0.f, 0.f, 0.f};

    for (int k0 = 0; k0 < DD; k0 += 64) {
        const uint4* ap = (const uint4*)(A  + (size_t)(row0 + srow) * DD + k0 + sseg);
        const uint4* bp = (const uint4*)(BT + (size_t)(col0 + srow) * DD + k0 + sseg);
        uint4 a0 = ap[0], a1 = ap[1], a2 = ap[2], a3 = ap[3];
        uint4 b0 = bp[0], b1 = bp[1], b2 = bp[2], b3 = bp[3];
        __syncthreads();
        *(uint4*)&Ash[srow][sseg +  0] = a0;
        *(uint4*)&Ash[srow][sseg +  8] = a1;
        *(uint4*)&Ash[srow][sseg + 16] = a2;
        *(uint4*)&Ash[srow][sseg + 24] = a3;
        *(uint4*)&Bsh[srow][sseg +  0] = b0;
        *(uint4*)&Bsh[srow][sseg +  8] = b1;
        *(uint4*)&Bsh[srow][sseg + 16] = b2;
        *(uint4*)&Bsh[srow][sseg + 24] = b3;
        __syncthreads();
        #pragma unroll
        for (int ks = 0; ks < 2; ks++) {
            short8 af[4], bf[4];
            #pragma unroll
            for (int i = 0; i < 4; i++)
                af[i] = *(const short8*)&Ash[moff + i * 16 + li][ks * 32 + grp * 8];
            #pragma unroll
            for (int j = 0; j < 4; j++)
                bf[j] = *(const short8*)&Bsh[noff + j * 16 + li][ks * 32 + grp * 8];
            #pragma unroll
            for (int i = 0; i < 4; i++)
                #pragma unroll
                for (int j = 0; j < 4; j++)
                    o[i][j] = __builtin_amdgcn_mfma_f32_16x16x32_bf16(
                        af[i], bf[j], o[i][j], 0, 0, 0);
        }
    }

    const bool f32 = flags[0] != 0;
    float bv[4];
    #pragma unroll
    for (int j = 0; j < 4; j++)
        bv[j] = load1(bias, col0 + noff + j * 16 + li, f32);

    #pragma unroll
    for (int i = 0; i < 4; i++) {
        #pragma unroll
        for (int r = 0; r < 4; r++) {
            int grow = row0 + moff + i * 16 + grp * 4 + r;
            #pragma unroll
            for (int j = 0; j < 4; j++) {
                int gcol = col0 + noff + j * 16 + li;
                float v = o[i][j][r] + bv[j];
                if (MODE == 0) {
                    ((unsigned short*)outp)[(size_t)grow * NCOL + gcol] = f2bf(v);
                } else {
                    int b = grow / RTOT, rr = grow % RTOT;
                    size_t dst = (rr < PP)
                        ? ((size_t)(b * PP + rr) * DD + gcol)
                        : ((size_t)BS * PP * DD + (size_t)(b * NN + (rr - PP)) * DD + gcol);
                    ((float*)outp)[dst] = v;
                }
            }
        }
    }
}

// ---------------------------------------------------------------------------
// Merged MFMA flash attention (cross + self in one grid), lean softmax via
// additive mask bias, optional packed-V^T staging, optional split-K (SPL=2).
// ---------------------------------------------------------------------------
template<bool PACKED, int SPL>
__global__ __launch_bounds__(256) void fattn2_kernel(
    const unsigned short* __restrict__ qkv,
    const unsigned short* __restrict__ VtG,      // used if PACKED
    const float* __restrict__ mb,                // additive bias [BS*RTOT]
    unsigned short* __restrict__ attn_out,       // used if SPL==1
    unsigned short* __restrict__ part_o,         // used if SPL>1 (unnormalized, bf16)
    float* __restrict__ part_ml)                 // used if SPL>1 (m,l per row)
{
    const int CB = BS * HH * (NN / 64);   // 768
    const int SB = BS * HH * (PP / 64);   // 192

    int bid = blockIdx.x;
    bool cross; int chunk, v;
    if (bid < CB * SPL) { cross = true;  chunk = bid / CB; v = bid % CB; }
    else { int s = bid - CB * SPL; cross = false; chunk = s / SB; v = s % SB; }
    const int nqb  = cross ? (NN / 64) : (PP / 64);
    const int q0   = (v % nqb) * 64;
    const int h    = (v / nqb) % HH;
    const int b    = v / (nqb * HH);
    const int QOFF = cross ? PP : 0;
    const int NT   = cross ? (RTOT / 64) : (PP / 64);
    const int tpc  = NT / SPL;
    const int t_beg = chunk * tpc, t_end = chunk * tpc + tpc;
    const int rowbase = cross ? ((b * HH + h) * NN + q0)
                              : (CROWS + (b * HH + h) * PP + q0);

    alignas(16) __shared__ unsigned short Ks[64][72];
    alignas(16) __shared__ unsigned short Vt[64][72];
    alignas(16) __shared__ unsigned short Psm[4][16][72];

    const int tid  = threadIdx.x;
    const int w    = tid >> 6;
    const int lane = tid & 63;
    const int grp  = lane >> 4;
    const int li   = lane & 15;
    const int lr   = tid >> 2;
    const int ld0  = (tid & 3) << 4;

    short8 qf[2];
    {
        const unsigned short* qp = qkv +
            (size_t)(b * RTOT + QOFF + q0 + w * 16 + li) * QKVC + h * HD + grp * 8;
        qf[0] = *(const short8*)(qp);
        qf[1] = *(const short8*)(qp + 32);
    }

    floatx4 o[4] = {{0.f,0.f,0.f,0.f},{0.f,0.f,0.f,0.f},
                    {0.f,0.f,0.f,0.f},{0.f,0.f,0.f,0.f}};
    float mrun[4] = {-3e38f, -3e38f, -3e38f, -3e38f};
    float lrun[4] = {0.f, 0.f, 0.f, 0.f};

    for (int t = t_beg; t < t_end; t++) {
        const int m0 = t * 64;
        __syncthreads();
        // ---- stage K (natural copy) ----
        {
            const unsigned short* kp = qkv +
                (size_t)(b * RTOT + m0 + lr) * QKVC + DD + h * HD + ld0;
            *(uint4*)&Ks[lr][ld0]     = ((const uint4*)kp)[0];
            *(uint4*)&Ks[lr][ld0 + 8] = ((const uint4*)kp)[1];
        }
        // ---- stage V^T ----
        if (PACKED) {
            const unsigned short* vp = VtG +
                ((size_t)(b * HH + h) * HD + lr) * RTOT + m0 + ld0;
            *(uint4*)&Vt[lr][ld0]     = ((const uint4*)vp)[0];
            *(uint4*)&Vt[lr][ld0 + 8] = ((const uint4*)vp)[1];
        } else {
            const unsigned short* vp = qkv +
                (size_t)(b * RTOT + m0 + lr) * QKVC + 2 * DD + h * HD + ld0;
            unsigned short tmp[16];
            *(uint4*)&tmp[0] = ((const uint4*)vp)[0];
            *(uint4*)&tmp[8] = ((const uint4*)vp)[1];
            #pragma unroll
            for (int j = 0; j < 16; j++) Vt[ld0 + j][lr] = tmp[j];
        }
        __syncthreads();

        // ---- S = Q K^T ----
        floatx4 sf[4];
        #pragma unroll
        for (int n = 0; n < 4; n++) {
            floatx4 acc = {0.f, 0.f, 0.f, 0.f};
            short8 kb0 = *(const short8*)&Ks[n * 16 + li][grp * 8];
            short8 kb1 = *(const short8*)&Ks[n * 16 + li][32 + grp * 8];
            acc = __builtin_amdgcn_mfma_f32_16x16x32_bf16(qf[0], kb0, acc, 0, 0, 0);
            acc = __builtin_amdgcn_mfma_f32_16x16x32_bf16(qf[1], kb1, acc, 0, 0, 0);
            sf[n] = acc;
        }

        float mbv[4];
        #pragma unroll
        for (int n = 0; n < 4; n++)
            mbv[n] = mb[b * RTOT + m0 + n * 16 + li];

        // ---- lean online softmax ----
        #pragma unroll
        for (int r = 0; r < 4; r++) {
            float sv[4];
            #pragma unroll
            for (int n = 0; n < 4; n++)
                sv[n] = fmaf(sf[n][r], 0.125f, mbv[n]);
            float tm = fmaxf(fmaxf(sv[0], sv[1]), fmaxf(sv[2], sv[3]));
            #pragma unroll
            for (int off = 1; off < 16; off <<= 1)
                tm = fmaxf(tm, __shfl_xor(tm, off));
            float mnew = fmaxf(mrun[r], tm);
            float al = __expf(mrun[r] - mnew);
            float p[4], ts = 0.f;
            #pragma unroll
            for (int n = 0; n < 4; n++) {
                p[n] = __expf(sv[n] - mnew);   // masked -> exp(-1e30-m) == 0
                ts += p[n];
            }
            #pragma unroll
            for (int off = 1; off < 16; off <<= 1)
                ts += __shfl_xor(ts, off);
            mrun[r] = mnew;
            lrun[r] = lrun[r] * al + ts;
            #pragma unroll
            for (int n = 0; n < 4; n++) {
                o[n][r] *= al;
                Psm[w][grp * 4 + r][n * 16 + li] = f2bf(p[n]);
            }
        }
        __syncthreads();

        // ---- O += P V ----
        #pragma unroll
        for (int s2 = 0; s2 < 2; s2++) {
            short8 pa = *(const short8*)&Psm[w][li][s2 * 32 + grp * 8];
            #pragma unroll
            for (int n2 = 0; n2 < 4; n2++) {
                short8 vf = *(const short8*)&Vt[n2 * 16 + li][s2 * 32 + grp * 8];
                o[n2] = __builtin_amdgcn_mfma_f32_16x16x32_bf16(pa, vf, o[n2], 0, 0, 0);
            }
        }
    }

    // ---- epilogue ----
    if (SPL > 1) {
        #pragma unroll
        for (int r = 0; r < 4; r++) {
            size_t row = (size_t)chunk * TROWS + rowbase + w * 16 + grp * 4 + r;
            #pragma unroll
            for (int n2 = 0; n2 < 4; n2++)
                part_o[row * 64 + n2 * 16 + li] = f2bf(o[n2][r]);
            if (li == 0) {
                part_ml[row * 2]     = mrun[r];
                part_ml[row * 2 + 1] = lrun[r];
            }
        }
    } else {
        #pragma unroll
        for (int r = 0; r < 4; r++) {
            float inv = 1.0f / lrun[r];
            int qloc = q0 + w * 16 + grp * 4 + r;
            if (cross) {
                size_t row = (size_t)(b * RTOT + PP + qloc);
                #pragma unroll
                for (int n2 = 0; n2 < 4; n2++)
                    attn_out[row * DD + h * HD + n2 * 16 + li] = f2bf(o[n2][r] * inv);
            } else {
                #pragma unroll
                for (int n2 = 0; n2 < 4; n2++) {
                    int dc = n2 * 16 + li;
                    int f = h * (HD * PP) + dc * PP + qloc;
                    attn_out[(size_t)(b * RTOT + f / DD) * DD + (f % DD)]
                        = f2bf(o[n2][r] * inv);
                }
            }
        }
    }
}

// ---------------------------------------------------------------------------
// Split-K combine: merge 2 chunks per row, normalize, store to attn layout.
// Grid TROWS/4 x 256; one wave per row, one lane per dv.
// ---------------------------------------------------------------------------
__global__ __launch_bounds__(256) void combine_kernel(
    const unsigned short* __restrict__ part_o,
    const float* __restrict__ part_ml,
    unsigned short* __restrict__ attn_out)
{
    const int row = blockIdx.x * 4 + (threadIdx.x >> 6);
    const int dv  = threadIdx.x & 63;
    float m1 = part_ml[(size_t)row * 2],             l1 = part_ml[(size_t)row * 2 + 1];
    float m2 = part_ml[((size_t)TROWS + row) * 2],   l2 = part_ml[((size_t)TROWS + row) * 2 + 1];
    float M  = fmaxf(m1, m2);
    float w1 = __expf(m1 - M), w2 = __expf(m2 - M);
    float o1 = bf2f(part_o[(size_t)row * 64 + dv]);
    float o2 = bf2f(part_o[((size_t)TROWS + row) * 64 + dv]);
    float res = (w1 * o1 + w2 * o2) / (w1 * l1 + w2 * l2);
    if (row < CROWS) {
        int b = row / (HH * NN), rem = row % (HH * NN);
        int h = rem / NN, n = rem % NN;
        attn_out[(size_t)(b * RTOT + PP + n) * DD + h * HD + dv] = f2bf(res);
    } else {
        int r2 = row - CROWS;
        int b = r2 / (HH * PP), rem = r2 % (HH * PP);
        int h = rem / PP, p = rem % PP;
        int f = h * (HD * PP) + dv * PP + p;
        attn_out[(size_t)(b * RTOT + f / DD) * DD + (f % DD)] = f2bf(res);
    }
}

// ---------------------------------------------------------------------------
// Round-9 fattn (kept as fallback tier).
// ---------------------------------------------------------------------------
template<int MODE>
__global__ __launch_bounds__(256) void fattn_kernel(
    const __hip_bfloat16* __restrict__ qkv,
    const void* __restrict__ mask,
    const int* __restrict__ flags,
    __hip_bfloat16* __restrict__ attn_out)
{
    constexpr int NQ    = (MODE == 0) ? NN : PP;
    constexpr int NK    = (MODE == 0) ? RTOT : PP;
    constexpr int QOFF  = (MODE == 0) ? PP : 0;
    constexpr int NTILE = NK / 64;

    alignas(16) __shared__ unsigned short Ks[64][72];
    alignas(16) __shared__ unsigned short Vt[64][72];
    alignas(16) __shared__ unsigned short Psm[4][16][72];

    const int tid   = threadIdx.x;
    const int w     = tid >> 6;
    const int lane  = tid & 63;
    const int grp   = lane >> 4;
    const int li    = lane & 15;
    const int nqb   = NQ / 64;
    const int q0    = (blockIdx.x % nqb) * 64;
    const int h     = (blockIdx.x / nqb) % HH;
    const int b     = blockIdx.x / (nqb * HH);
    const int mtype = flags[1];

    const unsigned short* qkv_u = (const unsigned short*)qkv;
    const int lr  = tid >> 2;
    const int ld0 = (tid & 3) << 4;

    short8 qf[2];
    {
        const unsigned short* qp = qkv_u +
            (size_t)(b * RTOT + QOFF + q0 + w * 16 + li) * QKVC + h * HD + grp * 8;
        qf[0] = *(const short8*)(qp);
        qf[1] = *(const short8*)(qp + 32);
    }

    floatx4 o[4] = {{0.f,0.f,0.f,0.f},{0.f,0.f,0.f,0.f},
                    {0.f,0.f,0.f,0.f},{0.f,0.f,0.f,0.f}};
    float mrun[4] = {-3e38f, -3e38f, -3e38f, -3e38f};
    float lrun[4] = {0.f, 0.f, 0.f, 0.f};

    for (int t = 0; t < NTILE; t++) {
        const int m0 = t * 64;
        __syncthreads();
        {
            const unsigned short* kp = qkv_u +
                (size_t)(b * RTOT + m0 + lr) * QKVC + DD + h * HD + ld0;
            *(uint4*)&Ks[lr][ld0]     = ((const uint4*)kp)[0];
            *(uint4*)&Ks[lr][ld0 + 8] = ((const uint4*)kp)[1];
            const unsigned short* vp = kp + DD;
            unsigned short tmp[16];
            *(uint4*)&tmp[0] = ((const uint4*)vp)[0];
            *(uint4*)&tmp[8] = ((const uint4*)vp)[1];
            #pragma unroll
            for (int j = 0; j < 16; j++) Vt[ld0 + j][lr] = tmp[j];
        }
        __syncthreads();

        floatx4 sf[4];
        #pragma unroll
        for (int n = 0; n < 4; n++) {
            floatx4 acc = {0.f, 0.f, 0.f, 0.f};
            short8 kb0 = *(const short8*)&Ks[n * 16 + li][grp * 8];
            short8 kb1 = *(const short8*)&Ks[n * 16 + li][32 + grp * 8];
            acc = __builtin_amdgcn_mfma_f32_16x16x32_bf16(qf[0], kb0, acc, 0, 0, 0);
            acc = __builtin_amdgcn_mfma_f32_16x16x32_bf16(qf[1], kb1, acc, 0, 0, 0);
            sf[n] = acc;
        }

        bool mk[4];
        #pragma unroll
        for (int n = 0; n < 4; n++) {
            int m = m0 + n * 16 + li;
            mk[n] = (m < PP) && mask_at(mask, b * PP + m, mtype);
        }

        #pragma unroll
        for (int r = 0; r < 4; r++) {
            float sv[4];
            #pragma unroll
            for (int n = 0; n < 4; n++)
                sv[n] = mk[n] ? -1e30f : sf[n][r] * 0.125f;
            float tm = fmaxf(fmaxf(sv[0], sv[1]), fmaxf(sv[2], sv[3]));
            #pragma unroll
            for (int off = 1; off < 16; off <<= 1)
                tm = fmaxf(tm, __shfl_xor(tm, off));
            float mnew = fmaxf(mrun[r], tm);
            float al = __expf(mrun[r] - mnew);
            float p[4], ts = 0.f;
            #pragma unroll
            for (int n = 0; n < 4; n++) {
                p[n] = (sv[n] < -1e29f) ? 0.f : __expf(sv[n] - mnew);
                ts += p[n];
            }
            #pragma unroll
            for (int off = 1; off < 16; off <<= 1)
                ts += __shfl_xor(ts, off);
            mrun[r] = mnew;
            lrun[r] = lrun[r] * al + ts;
            #pragma unroll
            for (int n = 0; n < 4; n++) {
                o[n][r] *= al;
                Psm[w][grp * 4 + r][n * 16 + li] = f2bf(p[n]);
            }
        }
        __syncthreads();

        #pragma unroll
        for (int s2 = 0; s2 < 2; s2++) {
            short8 pa = *(const short8*)&Psm[w][li][s2 * 32 + grp * 8];
            #pragma unroll
            for (int n2 = 0; n2 < 4; n2++) {
                short8 vf = *(const short8*)&Vt[n2 * 16 + li][s2 * 32 + grp * 8];
                o[n2] = __builtin_amdgcn_mfma_f32_16x16x32_bf16(pa, vf, o[n2], 0, 0, 0);
            }
        }
    }

    unsigned short* ao = (unsigned short*)attn_out;
    #pragma unroll
    for (int r = 0; r < 4; r++) {
        float inv = 1.0f / lrun[r];
        int qloc = q0 + w * 16 + grp * 4 + r;
        if (MODE == 0) {
            size_t row = (size_t)(b * RTOT + PP + qloc);
            #pragma unroll
            for (int n2 = 0; n2 < 4; n2++)
                ao[row * DD + h * HD + n2 * 16 + li] = f2bf(o[n2][r] * inv);
        } else {
            #pragma unroll
            for (int n2 = 0; n2 < 4; n2++) {
                int dc = n2 * 16 + li;
                int f = h * (HD * PP) + dc * PP + qloc;
                ao[(size_t)(b * RTOT + f / DD) * DD + (f % DD)] = f2bf(o[n2][r] * inv);
            }
        }
    }
}

// ---------------------------------------------------------------------------
// Vector GEMM fallback (last-resort tier).
// ---------------------------------------------------------------------------
template<int MODE, int NCOL, typename OutT>
__global__ __launch_bounds__(256) void gemm_kernel(
    const void* __restrict__ A0, const void* __restrict__ A1,
    const void* __restrict__ W, const void* __restrict__ bias,
    const int* __restrict__ flags, OutT* __restrict__ out)
{
    const bool f32 = flags[0] != 0;
    alignas(16) __shared__ float As[16][68];
    alignas(16) __shared__ float Bsh2[16][68];
    const int tid  = threadIdx.x;
    const int row0 = blockIdx.y * 64;
    const int col0 = blockIdx.x * 64;
    const int ty = tid >> 4, tx = tid & 15;
    const int a_row = tid >> 2;
    const int a_k4  = (tid & 3) * 4;
    const int grow  = row0 + a_row;
    const void* abase; size_t aoff; bool af32;
    if (MODE == 0) {
        int b = grow / RTOT, r = grow % RTOT;
        if (r < NN) { abase = A0; aoff = (size_t)(b * NN + r) * DD; }
        else        { abase = A1; aoff = (size_t)(b * PP + (r - NN)) * DD; }
        af32 = f32;
    } else {
        abase = A0; aoff = (size_t)grow * DD; af32 = false;
    }
    const int b_k  = tid >> 4;
    const int b_n4 = (tid & 15) * 4;
    float acc[4][4] = {};
    for (int k0 = 0; k0 < DD; k0 += 16) {
        float4 fa = load4(abase, aoff + k0 + a_k4, af32);
        As[a_k4 + 0][a_row] = fa.x;
        As[a_k4 + 1][a_row] = fa.y;
        As[a_k4 + 2][a_row] = fa.z;
        As[a_k4 + 3][a_row] = fa.w;
        float4 fb = load4(W, (size_t)(k0 + b_k) * NCOL + col0 + b_n4, f32);
        *(float4*)&Bsh2[b_k][b_n4] = fb;
        __syncthreads();
        #pragma unroll
        for (int kk = 0; kk < 16; kk++) {
            float4 av = *(const float4*)&As[kk][ty * 4];
            float4 bvv = *(const float4*)&Bsh2[kk][tx * 4];
            float a_[4] = {av.x, av.y, av.z, av.w};
            float b_[4] = {bvv.x, bvv.y, bvv.z, bvv.w};
            #pragma unroll
            for (int i = 0; i < 4; i++)
                #pragma unroll
                for (int j = 0; j < 4; j++)
                    acc[i][j] += a_[i] * b_[j];
        }
        __syncthreads();
    }
    #pragma unroll
    for (int i = 0; i < 4; i++) {
        int gr = row0 + ty * 4 + i;
        #pragma unroll
        for (int j = 0; j < 4; j++) {
            int gc = col0 + tx * 4 + j;
            float v = acc[i][j] + load1(bias, gc, f32);
            if (MODE == 0) {
                store_out(out, (size_t)gr * NCOL + gc, v);
            } else {
                int b = gr / RTOT, r = gr % RTOT;
                size_t dst = (r < PP)
                    ? ((size_t)(b * PP + r) * DD + gc)
                    : ((size_t)BS * PP * DD + (size_t)(b * NN + (r - PP)) * DD + gc);
                store_out(out, dst, v);
            }
        }
    }
}

// ---------------------------------------------------------------------------
extern "C" void kernel_launch(void* const* d_in, const int* in_sizes, int n_in,
                              void* d_out, int out_size, void* d_ws, size_t ws_size,
                              hipStream_t stream) {
    const void *xs = nullptr, *xq = nullptr, *mask = nullptr,
               *qkv_w = nullptr, *qkv_b = nullptr, *proj_w = nullptr, *proj_b = nullptr;
    for (int i = 0; i < n_in; i++) {
        switch (in_sizes[i]) {
            case BS * PP * DD:   xs     = d_in[i]; break;
            case BS * NN * DD:   xq     = d_in[i]; break;
            case BS * PP:        mask   = d_in[i]; break;
            case DD * QKVC:      qkv_w  = d_in[i]; break;
            case QKVC:           qkv_b  = d_in[i]; break;
            case DD * DD:        proj_w = d_in[i]; break;
            case DD:             proj_b = d_in[i]; break;
        }
    }
    if (!xs || !xq || !mask || !qkv_w || !qkv_b || !proj_w || !proj_b) {
        xs = d_in[0]; xq = d_in[1]; mask = d_in[2];
        qkv_w = d_in[3]; qkv_b = d_in[4]; proj_w = d_in[5]; proj_b = d_in[6];
    }
    float* out = (float*)d_out;

    // ---- new layout (tiers A/B/C) ----
    const size_t off_mb   = 256;
    const size_t off_full = off_mb   + (size_t)BS * RTOT * 4;        // 20,736
    const size_t off_ab   = off_full + (size_t)MTOT * QKVC * 2;
    const size_t off_w    = off_ab   + (size_t)MTOT * DD * 2;
    const size_t off_wp   = off_w    + (size_t)QKVC * DD * 2;
    const size_t off_vt   = off_wp   + (size_t)DD * DD * 2;          // need_C end
    const size_t off_po   = off_vt   + (size_t)BS * HH * HD * RTOT * 2; // need_B end
    const size_t off_ml   = off_po   + (size_t)2 * TROWS * 64 * 2;
    const size_t need_A   = off_ml   + (size_t)2 * TROWS * 2 * 4;
    const size_t need_B   = off_po;
    const size_t need_C   = off_vt;

    // ---- round-9 layout (tier R9) ----
    const size_t r_full = 256;
    const size_t r_ab   = r_full + (size_t)MTOT * QKVC * 2;
    const size_t r_wq   = r_ab   + (size_t)MTOT * DD * 2;
    const size_t r_wp   = r_wq   + (size_t)QKVC * DD * 2;
    const size_t need_R = r_wp   + (size_t)DD * DD * 2;

    int* flags = (int*)d_ws;
    detect_kernel<<<1, 256, 0, stream>>>(qkv_w, mask, flags);

    if (ws_size >= need_C) {
        float* mb               = (float*)((char*)d_ws + off_mb);
        unsigned short* fullqkv = (unsigned short*)((char*)d_ws + off_full);
        unsigned short* attn    = (unsigned short*)((char*)d_ws + off_ab);
        unsigned short* WqkvT   = (unsigned short*)((char*)d_ws + off_w);
        unsigned short* WprojT  = (unsigned short*)((char*)d_ws + off_wp);
        unsigned short* VtG     = (unsigned short*)((char*)d_ws + off_vt);
        unsigned short* part_o  = (unsigned short*)((char*)d_ws + off_po);
        float* part_ml          = (float*)((char*)d_ws + off_ml);

        maskbias_kernel<<<1, 256, 0, stream>>>(mask, flags, mb);
        concat_convert_kernel<<<MTOT, 192, 0, stream>>>(xq, xs, flags, attn /*as Abf*/);
        transpose_kernel<<<dim3(QKVC / 64, DD / 64), 256, 0, stream>>>(
            qkv_w, DD, QKVC, flags, WqkvT);
        transpose_kernel<<<dim3(DD / 64, DD / 64), 256, 0, stream>>>(
            proj_w, DD, DD, flags, WprojT);

        mgemm_kernel<0, QKVC><<<dim3(QKVC / 128, MTOT / 128), 256, 0, stream>>>(
            attn /*Abf*/, WqkvT, qkv_b, flags, (void*)fullqkv);

        const int CB = BS * HH * (NN / 64), SB = BS * HH * (PP / 64);
        if (ws_size >= need_A) {
            vtprep_kernel<<<dim3(RTOT / 64, BS * HH), 256, 0, stream>>>(fullqkv, VtG);
            fattn2_kernel<true, 2><<<(CB + SB) * 2, 256, 0, stream>>>(
                fullqkv, VtG, mb, nullptr, part_o, part_ml);
            combine_kernel<<<TROWS / 4, 256, 0, stream>>>(part_o, part_ml, attn);
        } else if (ws_size >= need_B) {
            vtprep_kernel<<<dim3(RTOT / 64, BS * HH), 256, 0, stream>>>(fullqkv, VtG);
            fattn2_kernel<true, 1><<<CB + SB, 256, 0, stream>>>(
                fullqkv, VtG, mb, attn, nullptr, nullptr);
        } else {
            fattn2_kernel<false, 1><<<CB + SB, 256, 0, stream>>>(
                fullqkv, nullptr, mb, attn, nullptr, nullptr);
        }

        mgemm_kernel<1, DD><<<dim3(DD / 128, MTOT / 128), 256, 0, stream>>>(
            attn, WprojT, proj_b, flags, (void*)out);
    } else if (ws_size >= need_R) {
        unsigned short* fullqkv = (unsigned short*)((char*)d_ws + r_full);
        unsigned short* attn    = (unsigned short*)((char*)d_ws + r_ab);
        unsigned short* WqkvT   = (unsigned short*)((char*)d_ws + r_wq);
        unsigned short* WprojT  = (unsigned short*)((char*)d_ws + r_wp);

        concat_convert_kernel<<<MTOT, 192, 0, stream>>>(xq, xs, flags, attn);
        transpose_kernel<<<dim3(QKVC / 64, DD / 64), 256, 0, stream>>>(
            qkv_w, DD, QKVC, flags, WqkvT);
        transpose_kernel<<<dim3(DD / 64, DD / 64), 256, 0, stream>>>(
            proj_w, DD, DD, flags, WprojT);
        mgemm_kernel<0, QKVC><<<dim3(QKVC / 128, MTOT / 128), 256, 0, stream>>>(
            attn, WqkvT, qkv_b, flags, (void*)fullqkv);
        fattn_kernel<0><<<BS * HH * (NN / 64), 256, 0, stream>>>(
            (const __hip_bfloat16*)fullqkv, mask, flags, (__hip_bfloat16*)attn);
        fattn_kernel<1><<<BS * HH * (PP / 64), 256, 0, stream>>>(
            (const __hip_bfloat16*)fullqkv, mask, flags, (__hip_bfloat16*)attn);
        mgemm_kernel<1, DD><<<dim3(DD / 128, MTOT / 128), 256, 0, stream>>>(
            attn, WprojT, proj_b, flags, (void*)out);
    } else {
        __hip_bfloat16* fullqkv = (__hip_bfloat16*)((char*)d_ws + 256);
        __hip_bfloat16* attn    = fullqkv + (size_t)MTOT * QKVC;
        gemm_kernel<0, QKVC, __hip_bfloat16>
            <<<dim3(QKVC / 64, MTOT / 64), 256, 0, stream>>>(
            xq, xs, qkv_w, qkv_b, flags, fullqkv);
        fattn_kernel<0><<<BS * HH * (NN / 64), 256, 0, stream>>>(fullqkv, mask, flags, attn);
        fattn_kernel<1><<<BS * HH * (PP / 64), 256, 0, stream>>>(fullqkv, mask, flags, attn);
        gemm_kernel<1, DD, float>
            <<<dim3(DD / 64, MTOT / 64), 256, 0, stream>>>(
            attn, nullptr, proj_w, proj_b, flags, out);
    }
}

// Round 11
// 274.701 us; speedup vs baseline: 28.1736x; 1.1209x over previous
//
#include <hip/hip_runtime.h>
#include <hip/hip_bf16.h>

#define BS   2
#define PP   512
#define NN   2048
#define DD   768
#define HH   12
#define HD   64
#define RTOT 2560   // P + N rows per batch
#define QKVC 2304   // 3*D
#define MTOT (BS * RTOT)       // 5120
#define CROWS (BS * HH * NN)   // 49152 cross q-rows
#define SROWS (BS * HH * PP)   // 12288 self q-rows
#define TROWS (CROWS + SROWS)  // 61440

typedef __attribute__((ext_vector_type(8))) short  short8;
typedef __attribute__((ext_vector_type(4))) float  floatx4;

__device__ __forceinline__ float bf2f(unsigned short x) {
    union { unsigned u; float f; } c; c.u = ((unsigned)x) << 16; return c.f;
}
__device__ __forceinline__ unsigned short f2bf(float x) {
    union { float f; unsigned u; } c; c.f = x;
    unsigned r = c.u + 0x7fff + ((c.u >> 16) & 1);   // RNE
    return (unsigned short)(r >> 16);
}

__device__ __forceinline__ float4 load4(const void* p, size_t i, bool f32) {
    if (f32) return *(const float4*)((const float*)p + i);
    ushort4 u = *(const ushort4*)((const unsigned short*)p + i);
    return make_float4(bf2f(u.x), bf2f(u.y), bf2f(u.z), bf2f(u.w));
}
__device__ __forceinline__ float load1(const void* p, size_t i, bool f32) {
    return f32 ? ((const float*)p)[i] : bf2f(((const unsigned short*)p)[i]);
}
__device__ __forceinline__ bool mask_at(const void* m, int idx, int mtype) {
    if (mtype == 2) return ((const float*)m)[idx] != 0.0f;
    if (mtype == 1) return ((const unsigned char*)m)[idx] != 0;
    return ((const int*)m)[idx] != 0;
}
__device__ __forceinline__ void store_out(float* p, size_t i, float v) { p[i] = v; }
__device__ __forceinline__ void store_out(__hip_bfloat16* p, size_t i, float v) {
    p[i] = __float2bfloat16(v);
}

// ---------------------------------------------------------------------------
// Runtime dtype detection. flags[0]: inputs f32?  flags[1]: mask type
// ---------------------------------------------------------------------------
__global__ void detect_kernel(const void* __restrict__ w,
                              const void* __restrict__ mask,
                              int* __restrict__ flags) {
    __shared__ int s_f32, s_fmask, s_bmask;
    if (threadIdx.x == 0) { s_f32 = 0; s_fmask = 0; s_bmask = 0; }
    __syncthreads();
    const unsigned short* u = (const unsigned short*)w;
    int bad = 0;
    for (int i = threadIdx.x * 2; i < 65536; i += 512) {
        float v = bf2f(u[i]);
        if (!(fabsf(v) <= 2.0f)) bad = 1;
    }
    if (bad) atomicOr(&s_f32, 1);
    const unsigned* mw = (const unsigned*)mask;
    int fm = 0, bm = 0;
    for (int i = threadIdx.x; i < 256; i += 256) {
        unsigned v = mw[i];
        if (v == 0x3F800000u) fm = 1;
        else if ((v & 0xFFFFFF00u) != 0u) bm = 1;
    }
    if (fm) atomicOr(&s_fmask, 1);
    if (bm) atomicOr(&s_bmask, 1);
    __syncthreads();
    if (threadIdx.x == 0) {
        flags[0] = s_f32;
        flags[1] = s_fmask ? 2 : (s_bmask ? 1 : 0);
    }
}

// ---------------------------------------------------------------------------
// Prep: mask -> additive bias mb[b*RTOT+m] = -1e30 (masked) / -15 (free).
// The -15 is the FIXED softmax reference: exp(s*0.125 - 15) never overflows
// (would need a 90-sigma score) and removes all online-max machinery.
// ---------------------------------------------------------------------------
__global__ __launch_bounds__(256) void maskbias_kernel(
    const void* __restrict__ mask, const int* __restrict__ flags,
    float* __restrict__ mb)
{
    const int mtype = flags[1];
    const int i = blockIdx.x * 256 + threadIdx.x;
    if (i >= BS * RTOT) return;
    int b = i / RTOT, m = i % RTOT;
    float v = -15.0f;
    if (m < PP && mask_at(mask, b * PP + m, mtype)) v = -1e30f;
    mb[i] = v;
}

// ---------------------------------------------------------------------------
// Prep: Abf[5120][768] bf16 = concat([xq, xs]) per batch.
// ---------------------------------------------------------------------------
__global__ __launch_bounds__(192) void concat_convert_kernel(
    const void* __restrict__ xq, const void* __restrict__ xs,
    const int* __restrict__ flags, unsigned short* __restrict__ Abf)
{
    const bool f32 = flags[0] != 0;
    const int r = blockIdx.x;
    const int b = r / RTOT, rr = r % RTOT;
    const void* src;
    size_t off;
    if (rr < NN) { src = xq; off = (size_t)(b * NN + rr) * DD; }
    else         { src = xs; off = (size_t)(b * PP + (rr - NN)) * DD; }
    const int t = threadIdx.x;
    float4 v = load4(src, off + t * 4, f32);
    ushort4 o;
    o.x = f2bf(v.x); o.y = f2bf(v.y); o.z = f2bf(v.z); o.w = f2bf(v.w);
    *(ushort4*)&Abf[(size_t)r * DD + t * 4] = o;
}

// ---------------------------------------------------------------------------
// Prep: out[C][R] bf16 = transpose(in[R][C]).
// ---------------------------------------------------------------------------
__global__ __launch_bounds__(256) void transpose_kernel(
    const void* __restrict__ in, int R, int C,
    const int* __restrict__ flags, unsigned short* __restrict__ out)
{
    const bool f32 = flags[0] != 0;
    __shared__ unsigned short T[64][65];
    const int c0 = blockIdx.x * 64, r0 = blockIdx.y * 64;
    const int col = threadIdx.x & 63;
    const int r4  = threadIdx.x >> 6;
    #pragma unroll
    for (int p = 0; p < 16; p++) {
        int row = p * 4 + r4;
        T[row][col] = f2bf(load1(in, (size_t)(r0 + row) * C + c0 + col, f32));
    }
    __syncthreads();
    #pragma unroll
    for (int p = 0; p < 16; p++) {
        int crow = p * 4 + r4;
        out[(size_t)(c0 + crow) * R + r0 + col] = T[col][crow];
    }
}

// ---------------------------------------------------------------------------
// Prep: VtG[(b*HH+h)][dv][m] bf16 = V^T per head, from fullqkv V block.
// ---------------------------------------------------------------------------
__global__ __launch_bounds__(256) void vtprep_kernel(
    const unsigned short* __restrict__ qkv, unsigned short* __restrict__ VtG)
{
    alignas(16) __shared__ unsigned short T[64][72];
    const int mt = blockIdx.x * 64;
    const int bh = blockIdx.y;
    const int b = bh / HH, h = bh % HH;
    const int lr  = threadIdx.x >> 2;
    const int ld0 = (threadIdx.x & 3) << 4;
    const unsigned short* vp = qkv +
        (size_t)(b * RTOT + mt + lr) * QKVC + 2 * DD + h * HD + ld0;
    *(uint4*)&T[lr][ld0]     = ((const uint4*)vp)[0];
    *(uint4*)&T[lr][ld0 + 8] = ((const uint4*)vp)[1];
    __syncthreads();
    unsigned short tmp[16];
    #pragma unroll
    for (int j = 0; j < 16; j++) tmp[j] = T[ld0 + j][lr];
    unsigned short* dst = VtG + ((size_t)bh * HD + lr) * RTOT + mt + ld0;
    *(uint4*)dst       = *(uint4*)&tmp[0];
    *(uint4*)(dst + 8) = *(uint4*)&tmp[8];
}

// ---------------------------------------------------------------------------
// MFMA GEMM: C[M][NCOL] = A @ BT^T + bias.
// ---------------------------------------------------------------------------
template<int MODE, int NCOL>
__global__ __launch_bounds__(256) void mgemm_kernel(
    const unsigned short* __restrict__ A,
    const unsigned short* __restrict__ BT,
    const void* __restrict__ bias,
    const int* __restrict__ flags,
    void* __restrict__ outp)
{
    alignas(16) __shared__ unsigned short Ash[128][72];
    alignas(16) __shared__ unsigned short Bsh[128][72];

    const int tid  = threadIdx.x;
    const int w    = tid >> 6;
    const int lane = tid & 63;
    const int grp  = lane >> 4;
    const int li   = lane & 15;
    const int row0 = blockIdx.y * 128;
    const int col0 = blockIdx.x * 128;
    const int moff = (w >> 1) * 64;
    const int noff = (w & 1) * 64;
    const int srow = tid >> 1;
    const int sseg = (tid & 1) * 32;

    floatx4 o[4][4];
    #pragma unroll
    for (int i = 0; i < 4; i++)
        #pragma unroll
        for (int j = 0; j < 4; j++)
            o[i][j] = (floatx4){0.f, 0.f, 0.f, 0.f};

    for (int k0 = 0; k0 < DD; k0 += 64) {
        const uint4* ap = (const uint4*)(A  + (size_t)(row0 + srow) * DD + k0 + sseg);
        const uint4* bp = (const uint4*)(BT + (size_t)(col0 + srow) * DD + k0 + sseg);
        uint4 a0 = ap[0], a1 = ap[1], a2 = ap[2], a3 = ap[3];
        uint4 b0 = bp[0], b1 = bp[1], b2 = bp[2], b3 = bp[3];
        __syncthreads();
        *(uint4*)&Ash[srow][sseg +  0] = a0;
        *(uint4*)&Ash[srow][sseg +  8] = a1;
        *(uint4*)&Ash[srow][sseg + 16] = a2;
        *(uint4*)&Ash[srow][sseg + 24] = a3;
        *(uint4*)&Bsh[srow][sseg +  0] = b0;
        *(uint4*)&Bsh[srow][sseg +  8] = b1;
        *(uint4*)&Bsh[srow][sseg + 16] = b2;
        *(uint4*)&Bsh[srow][sseg + 24] = b3;
        __syncthreads();
        #pragma unroll
        for (int ks = 0; ks < 2; ks++) {
            short8 af[4], bf[4];
            #pragma unroll
            for (int i = 0; i < 4; i++)
                af[i] = *(const short8*)&Ash[moff + i * 16 + li][ks * 32 + grp * 8];
            #pragma unroll
            for (int j = 0; j < 4; j++)
                bf[j] = *(const short8*)&Bsh[noff + j * 16 + li][ks * 32 + grp * 8];
            #pragma unroll
            for (int i = 0; i < 4; i++)
                #pragma unroll
                for (int j = 0; j < 4; j++)
                    o[i][j] = __builtin_amdgcn_mfma_f32_16x16x32_bf16(
                        af[i], bf[j], o[i][j], 0, 0, 0);
        }
    }

    const bool f32 = flags[0] != 0;
    float bv[4];
    #pragma unroll
    for (int j = 0; j < 4; j++)
        bv[j] = load1(bias, col0 + noff + j * 16 + li, f32);

    #pragma unroll
    for (int i = 0; i < 4; i++) {
        #pragma unroll
        for (int r = 0; r < 4; r++) {
            int grow = row0 + moff + i * 16 + grp * 4 + r;
            #pragma unroll
            for (int j = 0; j < 4; j++) {
                int gcol = col0 + noff + j * 16 + li;
                float v = o[i][j][r] + bv[j];
                if (MODE == 0) {
                    ((unsigned short*)outp)[(size_t)grow * NCOL + gcol] = f2bf(v);
                } else {
                    int b = grow / RTOT, rr = grow % RTOT;
                    size_t dst = (rr < PP)
                        ? ((size_t)(b * PP + rr) * DD + gcol)
                        : ((size_t)BS * PP * DD + (size_t)(b * NN + (rr - PP)) * DD + gcol);
                    ((float*)outp)[dst] = v;
                }
            }
        }
    }
}

// ---------------------------------------------------------------------------
// Merged MFMA flash attention, FIXED-MAX softmax (no cross-lane reductions
// in the tile loop, no O rescale). l accumulated per-lane, reduced once in
// the epilogue. mb carries the -15 reference (masked = -1e30).
// ---------------------------------------------------------------------------
template<bool PACKED, int SPL>
__global__ __launch_bounds__(256) void fattn2_kernel(
    const unsigned short* __restrict__ qkv,
    const unsigned short* __restrict__ VtG,      // used if PACKED
    const float* __restrict__ mb,                // additive bias [BS*RTOT]
    unsigned short* __restrict__ attn_out,       // used if SPL==1
    unsigned short* __restrict__ part_o,         // used if SPL>1 (unnormalized)
    float* __restrict__ part_l)                  // used if SPL>1 (l per row)
{
    const int CB = BS * HH * (NN / 64);   // 768
    const int SB = BS * HH * (PP / 64);   // 192

    int bid = blockIdx.x;
    bool cross; int chunk, v;
    if (bid < CB * SPL) { cross = true;  chunk = bid / CB; v = bid % CB; }
    else { int s = bid - CB * SPL; cross = false; chunk = s / SB; v = s % SB; }
    const int nqb  = cross ? (NN / 64) : (PP / 64);
    const int q0   = (v % nqb) * 64;
    const int h    = (v / nqb) % HH;
    const int b    = v / (nqb * HH);
    const int QOFF = cross ? PP : 0;
    const int NT   = cross ? (RTOT / 64) : (PP / 64);
    const int tpc  = NT / SPL;
    const int t_beg = chunk * tpc, t_end = chunk * tpc + tpc;
    const int rowbase = cross ? ((b * HH + h) * NN + q0)
                              : (CROWS + (b * HH + h) * PP + q0);

    alignas(16) __shared__ unsigned short Ks[64][72];
    alignas(16) __shared__ unsigned short Vt[64][72];
    alignas(16) __shared__ unsigned short Psm[4][16][72];

    const int tid  = threadIdx.x;
    const int w    = tid >> 6;
    const int lane = tid & 63;
    const int grp  = lane >> 4;
    const int li   = lane & 15;
    const int lr   = tid >> 2;
    const int ld0  = (tid & 3) << 4;

    short8 qf[2];
    {
        const unsigned short* qp = qkv +
            (size_t)(b * RTOT + QOFF + q0 + w * 16 + li) * QKVC + h * HD + grp * 8;
        qf[0] = *(const short8*)(qp);
        qf[1] = *(const short8*)(qp + 32);
    }

    floatx4 o[4] = {{0.f,0.f,0.f,0.f},{0.f,0.f,0.f,0.f},
                    {0.f,0.f,0.f,0.f},{0.f,0.f,0.f,0.f}};
    float lpart[4] = {0.f, 0.f, 0.f, 0.f};

    for (int t = t_beg; t < t_end; t++) {
        const int m0 = t * 64;
        __syncthreads();
        // ---- stage K ----
        {
            const unsigned short* kp = qkv +
                (size_t)(b * RTOT + m0 + lr) * QKVC + DD + h * HD + ld0;
            *(uint4*)&Ks[lr][ld0]     = ((const uint4*)kp)[0];
            *(uint4*)&Ks[lr][ld0 + 8] = ((const uint4*)kp)[1];
        }
        // ---- stage V^T ----
        if (PACKED) {
            const unsigned short* vp = VtG +
                ((size_t)(b * HH + h) * HD + lr) * RTOT + m0 + ld0;
            *(uint4*)&Vt[lr][ld0]     = ((const uint4*)vp)[0];
            *(uint4*)&Vt[lr][ld0 + 8] = ((const uint4*)vp)[1];
        } else {
            const unsigned short* vp = qkv +
                (size_t)(b * RTOT + m0 + lr) * QKVC + 2 * DD + h * HD + ld0;
            unsigned short tmp[16];
            *(uint4*)&tmp[0] = ((const uint4*)vp)[0];
            *(uint4*)&tmp[8] = ((const uint4*)vp)[1];
            #pragma unroll
            for (int j = 0; j < 16; j++) Vt[ld0 + j][lr] = tmp[j];
        }
        __syncthreads();

        // ---- S = Q K^T ----
        floatx4 sf[4];
        #pragma unroll
        for (int n = 0; n < 4; n++) {
            floatx4 acc = {0.f, 0.f, 0.f, 0.f};
            short8 kb0 = *(const short8*)&Ks[n * 16 + li][grp * 8];
            short8 kb1 = *(const short8*)&Ks[n * 16 + li][32 + grp * 8];
            acc = __builtin_amdgcn_mfma_f32_16x16x32_bf16(qf[0], kb0, acc, 0, 0, 0);
            acc = __builtin_amdgcn_mfma_f32_16x16x32_bf16(qf[1], kb1, acc, 0, 0, 0);
            sf[n] = acc;
        }

        float mbv[4];
        #pragma unroll
        for (int n = 0; n < 4; n++)
            mbv[n] = mb[b * RTOT + m0 + n * 16 + li];

        // ---- fixed-max softmax: p = exp(s/8 + mbv), lane-local l ----
        #pragma unroll
        for (int r = 0; r < 4; r++) {
            float p[4];
            #pragma unroll
            for (int n = 0; n < 4; n++)
                p[n] = __expf(fmaf(sf[n][r], 0.125f, mbv[n]));
            lpart[r] += (p[0] + p[1]) + (p[2] + p[3]);
            #pragma unroll
            for (int n = 0; n < 4; n++)
                Psm[w][grp * 4 + r][n * 16 + li] = f2bf(p[n]);
        }
        __syncthreads();

        // ---- O += P V ----
        #pragma unroll
        for (int s2 = 0; s2 < 2; s2++) {
            short8 pa = *(const short8*)&Psm[w][li][s2 * 32 + grp * 8];
            #pragma unroll
            for (int n2 = 0; n2 < 4; n2++) {
                short8 vf = *(const short8*)&Vt[n2 * 16 + li][s2 * 32 + grp * 8];
                o[n2] = __builtin_amdgcn_mfma_f32_16x16x32_bf16(pa, vf, o[n2], 0, 0, 0);
            }
        }
    }

    // ---- one-time l reduction across the 16 lanes of this grp ----
    float lfull[4];
    #pragma unroll
    for (int r = 0; r < 4; r++) {
        float l = lpart[r];
        #pragma unroll
        for (int off = 1; off < 16; off <<= 1)
            l += __shfl_xor(l, off);
        lfull[r] = l;
    }

    // ---- epilogue ----
    if (SPL > 1) {
        #pragma unroll
        for (int r = 0; r < 4; r++) {
            size_t row = (size_t)chunk * TROWS + rowbase + w * 16 + grp * 4 + r;
            #pragma unroll
            for (int n2 = 0; n2 < 4; n2++)
                part_o[row * 64 + n2 * 16 + li] = f2bf(o[n2][r]);
            if (li == 0) part_l[row] = lfull[r];
        }
    } else {
        #pragma unroll
        for (int r = 0; r < 4; r++) {
            float inv = 1.0f / lfull[r];
            int qloc = q0 + w * 16 + grp * 4 + r;
            if (cross) {
                size_t row = (size_t)(b * RTOT + PP + qloc);
                #pragma unroll
                for (int n2 = 0; n2 < 4; n2++)
                    attn_out[row * DD + h * HD + n2 * 16 + li] = f2bf(o[n2][r] * inv);
            } else {
                #pragma unroll
                for (int n2 = 0; n2 < 4; n2++) {
                    int dc = n2 * 16 + li;
                    int f = h * (HD * PP) + dc * PP + qloc;
                    attn_out[(size_t)(b * RTOT + f / DD) * DD + (f % DD)]
                        = f2bf(o[n2][r] * inv);
                }
            }
        }
    }
}

// ---------------------------------------------------------------------------
// Split-K combine (fixed-max: plain sums, then normalize).
// ---------------------------------------------------------------------------
__global__ __launch_bounds__(256) void combine_kernel(
    const unsigned short* __restrict__ part_o,
    const float* __restrict__ part_l,
    unsigned short* __restrict__ attn_out)
{
    const int row = blockIdx.x * 4 + (threadIdx.x >> 6);
    const int dv  = threadIdx.x & 63;
    float l = part_l[row] + part_l[TROWS + row];
    float o1 = bf2f(part_o[(size_t)row * 64 + dv]);
    float o2 = bf2f(part_o[((size_t)TROWS + row) * 64 + dv]);
    float res = (o1 + o2) / l;
    if (row < CROWS) {
        int b = row / (HH * NN), rem = row % (HH * NN);
        int h = rem / NN, n = rem % NN;
        attn_out[(size_t)(b * RTOT + PP + n) * DD + h * HD + dv] = f2bf(res);
    } else {
        int r2 = row - CROWS;
        int b = r2 / (HH * PP), rem = r2 % (HH * PP);
        int h = rem / PP, p = rem % PP;
        int f = h * (HD * PP) + dv * PP + p;
        attn_out[(size_t)(b * RTOT + f / DD) * DD + (f % DD)] = f2bf(res);
    }
}

// ---------------------------------------------------------------------------
// Round-9 fattn (fallback tier, online softmax).
// ---------------------------------------------------------------------------
template<int MODE>
__global__ __launch_bounds__(256) void fattn_kernel(
    const __hip_bfloat16* __restrict__ qkv,
    const void* __restrict__ mask,
    const int* __restrict__ flags,
    __hip_bfloat16* __restrict__ attn_out)
{
    constexpr int NQ    = (MODE == 0) ? NN : PP;
    constexpr int NK    = (MODE == 0) ? RTOT : PP;
    constexpr int QOFF  = (MODE == 0) ? PP : 0;
    constexpr int NTILE = NK / 64;

    alignas(16) __shared__ unsigned short Ks[64][72];
    alignas(16) __shared__ unsigned short Vt[64][72];
    alignas(16) __shared__ unsigned short Psm[4][16][72];

    const int tid   = threadIdx.x;
    const int w     = tid >> 6;
    const int lane  = tid & 63;
    const int grp   = lane >> 4;
    const int li    = lane & 15;
    const int nqb   = NQ / 64;
    const int q0    = (blockIdx.x % nqb) * 64;
    const int h     = (blockIdx.x / nqb) % HH;
    const int b     = blockIdx.x / (nqb * HH);
    const int mtype = flags[1];

    const unsigned short* qkv_u = (const unsigned short*)qkv;
    const int lr  = tid >> 2;
    const int ld0 = (tid & 3) << 4;

    short8 qf[2];
    {
        const unsigned short* qp = qkv_u +
            (size_t)(b * RTOT + QOFF + q0 + w * 16 + li) * QKVC + h * HD + grp * 8;
        qf[0] = *(const short8*)(qp);
        qf[1] = *(const short8*)(qp + 32);
    }

    floatx4 o[4] = {{0.f,0.f,0.f,0.f},{0.f,0.f,0.f,0.f},
                    {0.f,0.f,0.f,0.f},{0.f,0.f,0.f,0.f}};
    float mrun[4] = {-3e38f, -3e38f, -3e38f, -3e38f};
    float lrun[4] = {0.f, 0.f, 0.f, 0.f};

    for (int t = 0; t < NTILE; t++) {
        const int m0 = t * 64;
        __syncthreads();
        {
            const unsigned short* kp = qkv_u +
                (size_t)(b * RTOT + m0 + lr) * QKVC + DD + h * HD + ld0;
            *(uint4*)&Ks[lr][ld0]     = ((const uint4*)kp)[0];
            *(uint4*)&Ks[lr][ld0 + 8] = ((const uint4*)kp)[1];
            const unsigned short* vp = kp + DD;
            unsigned short tmp[16];
            *(uint4*)&tmp[0] = ((const uint4*)vp)[0];
            *(uint4*)&tmp[8] = ((const uint4*)vp)[1];
            #pragma unroll
            for (int j = 0; j < 16; j++) Vt[ld0 + j][lr] = tmp[j];
        }
        __syncthreads();

        floatx4 sf[4];
        #pragma unroll
        for (int n = 0; n < 4; n++) {
            floatx4 acc = {0.f, 0.f, 0.f, 0.f};
            short8 kb0 = *(const short8*)&Ks[n * 16 + li][grp * 8];
            short8 kb1 = *(const short8*)&Ks[n * 16 + li][32 + grp * 8];
            acc = __builtin_amdgcn_mfma_f32_16x16x32_bf16(qf[0], kb0, acc, 0, 0, 0);
            acc = __builtin_amdgcn_mfma_f32_16x16x32_bf16(qf[1], kb1, acc, 0, 0, 0);
            sf[n] = acc;
        }

        bool mk[4];
        #pragma unroll
        for (int n = 0; n < 4; n++) {
            int m = m0 + n * 16 + li;
            mk[n] = (m < PP) && mask_at(mask, b * PP + m, mtype);
        }

        #pragma unroll
        for (int r = 0; r < 4; r++) {
            float sv[4];
            #pragma unroll
            for (int n = 0; n < 4; n++)
                sv[n] = mk[n] ? -1e30f : sf[n][r] * 0.125f;
            float tm = fmaxf(fmaxf(sv[0], sv[1]), fmaxf(sv[2], sv[3]));
            #pragma unroll
            for (int off = 1; off < 16; off <<= 1)
                tm = fmaxf(tm, __shfl_xor(tm, off));
            float mnew = fmaxf(mrun[r], tm);
            float al = __expf(mrun[r] - mnew);
            float p[4], ts = 0.f;
            #pragma unroll
            for (int n = 0; n < 4; n++) {
                p[n] = (sv[n] < -1e29f) ? 0.f : __expf(sv[n] - mnew);
                ts += p[n];
            }
            #pragma unroll
            for (int off = 1; off < 16; off <<= 1)
                ts += __shfl_xor(ts, off);
            mrun[r] = mnew;
            lrun[r] = lrun[r] * al + ts;
            #pragma unroll
            for (int n = 0; n < 4; n++) {
                o[n][r] *= al;
                Psm[w][grp * 4 + r][n * 16 + li] = f2bf(p[n]);
            }
        }
        __syncthreads();

        #pragma unroll
        for (int s2 = 0; s2 < 2; s2++) {
            short8 pa = *(const short8*)&Psm[w][li][s2 * 32 + grp * 8];
            #pragma unroll
            for (int n2 = 0; n2 < 4; n2++) {
                short8 vf = *(const short8*)&Vt[n2 * 16 + li][s2 * 32 + grp * 8];
                o[n2] = __builtin_amdgcn_mfma_f32_16x16x32_bf16(pa, vf, o[n2], 0, 0, 0);
            }
        }
    }

    unsigned short* ao = (unsigned short*)attn_out;
    #pragma unroll
    for (int r = 0; r < 4; r++) {
        float inv = 1.0f / lrun[r];
        int qloc = q0 + w * 16 + grp * 4 + r;
        if (MODE == 0) {
            size_t row = (size_t)(b * RTOT + PP + qloc);
            #pragma unroll
            for (int n2 = 0; n2 < 4; n2++)
                ao[row * DD + h * HD + n2 * 16 + li] = f2bf(o[n2][r] * inv);
        } else {
            #pragma unroll
            for (int n2 = 0; n2 < 4; n2++) {
                int dc = n2 * 16 + li;
                int f = h * (HD * PP) + dc * PP + qloc;
                ao[(size_t)(b * RTOT + f / DD) * DD + (f % DD)] = f2bf(o[n2][r] * inv);
            }
        }
    }
}

// ---------------------------------------------------------------------------
// Vector GEMM fallback (last-resort tier).
// ---------------------------------------------------------------------------
template<int MODE, int NCOL, typename OutT>
__global__ __launch_bounds__(256) void gemm_kernel(
    const void* __restrict__ A0, const void* __restrict__ A1,
    const void* __restrict__ W, const void* __restrict__ bias,
    const int* __restrict__ flags, OutT* __restrict__ out)
{
    const bool f32 = flags[0] != 0;
    alignas(16) __shared__ float As[16][68];
    alignas(16) __shared__ float Bsh2[16][68];
    const int tid  = threadIdx.x;
    const int row0 = blockIdx.y * 64;
    const int col0 = blockIdx.x * 64;
    const int ty = tid >> 4, tx = tid & 15;
    const int a_row = tid >> 2;
    const int a_k4  = (tid & 3) * 4;
    const int grow  = row0 + a_row;
    const void* abase; size_t aoff; bool af32;
    if (MODE == 0) {
        int b = grow / RTOT, r = grow % RTOT;
        if (r < NN) { abase = A0; aoff = (size_t)(b * NN + r) * DD; }
        else        { abase = A1; aoff = (size_t)(b * PP + (r - NN)) * DD; }
        af32 = f32;
    } else {
        abase = A0; aoff = (size_t)grow * DD; af32 = false;
    }
    const int b_k  = tid >> 4;
    const int b_n4 = (tid & 15) * 4;
    float acc[4][4] = {};
    for (int k0 = 0; k0 < DD; k0 += 16) {
        float4 fa = load4(abase, aoff + k0 + a_k4, af32);
        As[a_k4 + 0][a_row] = fa.x;
        As[a_k4 + 1][a_row] = fa.y;
        As[a_k4 + 2][a_row] = fa.z;
        As[a_k4 + 3][a_row] = fa.w;
        float4 fb = load4(W, (size_t)(k0 + b_k) * NCOL + col0 + b_n4, f32);
        *(float4*)&Bsh2[b_k][b_n4] = fb;
        __syncthreads();
        #pragma unroll
        for (int kk = 0; kk < 16; kk++) {
            float4 av = *(const float4*)&As[kk][ty * 4];
            float4 bvv = *(const float4*)&Bsh2[kk][tx * 4];
            float a_[4] = {av.x, av.y, av.z, av.w};
            float b_[4] = {bvv.x, bvv.y, bvv.z, bvv.w};
            #pragma unroll
            for (int i = 0; i < 4; i++)
                #pragma unroll
                for (int j = 0; j < 4; j++)
                    acc[i][j] += a_[i] * b_[j];
        }
        __syncthreads();
    }
    #pragma unroll
    for (int i = 0; i < 4; i++) {
        int gr = row0 + ty * 4 + i;
        #pragma unroll
        for (int j = 0; j < 4; j++) {
            int gc = col0 + tx * 4 + j;
            float v = acc[i][j] + load1(bias, gc, f32);
            if (MODE == 0) {
                store_out(out, (size_t)gr * NCOL + gc, v);
            } else {
                int b = gr / RTOT, r = gr % RTOT;
                size_t dst = (r < PP)
                    ? ((size_t)(b * PP + r) * DD + gc)
                    : ((size_t)BS * PP * DD + (size_t)(b * NN + (r - PP)) * DD + gc);
                store_out(out, dst, v);
            }
        }
    }
}

// ---------------------------------------------------------------------------
extern "C" void kernel_launch(void* const* d_in, const int* in_sizes, int n_in,
                              void* d_out, int out_size, void* d_ws, size_t ws_size,
                              hipStream_t stream) {
    const void *xs = nullptr, *xq = nullptr, *mask = nullptr,
               *qkv_w = nullptr, *qkv_b = nullptr, *proj_w = nullptr, *proj_b = nullptr;
    for (int i = 0; i < n_in; i++) {
        switch (in_sizes[i]) {
            case BS * PP * DD:   xs     = d_in[i]; break;
            case BS * NN * DD:   xq     = d_in[i]; break;
            case BS * PP:        mask   = d_in[i]; break;
            case DD * QKVC:      qkv_w  = d_in[i]; break;
            case QKVC:           qkv_b  = d_in[i]; break;
            case DD * DD:        proj_w = d_in[i]; break;
            case DD:             proj_b = d_in[i]; break;
        }
    }
    if (!xs || !xq || !mask || !qkv_w || !qkv_b || !proj_w || !proj_b) {
        xs = d_in[0]; xq = d_in[1]; mask = d_in[2];
        qkv_w = d_in[3]; qkv_b = d_in[4]; proj_w = d_in[5]; proj_b = d_in[6];
    }
    float* out = (float*)d_out;

    const size_t off_mb   = 256;
    const size_t off_full = off_mb   + (size_t)BS * RTOT * 4;
    const size_t off_ab   = off_full + (size_t)MTOT * QKVC * 2;
    const size_t off_w    = off_ab   + (size_t)MTOT * DD * 2;
    const size_t off_wp   = off_w    + (size_t)QKVC * DD * 2;
    const size_t off_vt   = off_wp   + (size_t)DD * DD * 2;
    const size_t off_po   = off_vt   + (size_t)BS * HH * HD * RTOT * 2;
    const size_t off_ml   = off_po   + (size_t)2 * TROWS * 64 * 2;
    const size_t need_A   = off_ml   + (size_t)2 * TROWS * 4;
    const size_t need_B   = off_po;
    const size_t need_C   = off_vt;

    const size_t r_full = 256;
    const size_t r_ab   = r_full + (size_t)MTOT * QKVC * 2;
    const size_t r_wq   = r_ab   + (size_t)MTOT * DD * 2;
    const size_t r_wp   = r_wq   + (size_t)QKVC * DD * 2;
    const size_t need_R = r_wp   + (size_t)DD * DD * 2;

    int* flags = (int*)d_ws;
    detect_kernel<<<1, 256, 0, stream>>>(qkv_w, mask, flags);

    if (ws_size >= need_C) {
        float* mb               = (float*)((char*)d_ws + off_mb);
        unsigned short* fullqkv = (unsigned short*)((char*)d_ws + off_full);
        unsigned short* attn    = (unsigned short*)((char*)d_ws + off_ab);
        unsigned short* WqkvT   = (unsigned short*)((char*)d_ws + off_w);
        unsigned short* WprojT  = (unsigned short*)((char*)d_ws + off_wp);
        unsigned short* VtG     = (unsigned short*)((char*)d_ws + off_vt);
        unsigned short* part_o  = (unsigned short*)((char*)d_ws + off_po);
        float* part_l           = (float*)((char*)d_ws + off_ml);

        maskbias_kernel<<<(BS * RTOT + 255) / 256, 256, 0, stream>>>(mask, flags, mb);
        concat_convert_kernel<<<MTOT, 192, 0, stream>>>(xq, xs, flags, attn /*as Abf*/);
        transpose_kernel<<<dim3(QKVC / 64, DD / 64), 256, 0, stream>>>(
            qkv_w, DD, QKVC, flags, WqkvT);
        transpose_kernel<<<dim3(DD / 64, DD / 64), 256, 0, stream>>>(
            proj_w, DD, DD, flags, WprojT);

        mgemm_kernel<0, QKVC><<<dim3(QKVC / 128, MTOT / 128), 256, 0, stream>>>(
            attn /*Abf*/, WqkvT, qkv_b, flags, (void*)fullqkv);

        const int CB = BS * HH * (NN / 64), SB = BS * HH * (PP / 64);
        if (ws_size >= need_A) {
            vtprep_kernel<<<dim3(RTOT / 64, BS * HH), 256, 0, stream>>>(fullqkv, VtG);
            fattn2_kernel<true, 2><<<(CB + SB) * 2, 256, 0, stream>>>(
                fullqkv, VtG, mb, nullptr, part_o, part_l);
            combine_kernel<<<TROWS / 4, 256, 0, stream>>>(part_o, part_l, attn);
        } else if (ws_size >= need_B) {
            vtprep_kernel<<<dim3(RTOT / 64, BS * HH), 256, 0, stream>>>(fullqkv, VtG);
            fattn2_kernel<true, 1><<<CB + SB, 256, 0, stream>>>(
                fullqkv, VtG, mb, attn, nullptr, nullptr);
        } else {
            fattn2_kernel<false, 1><<<CB + SB, 256, 0, stream>>>(
                fullqkv, nullptr, mb, attn, nullptr, nullptr);
        }

        mgemm_kernel<1, DD><<<dim3(DD / 128, MTOT / 128), 256, 0, stream>>>(
            attn, WprojT, proj_b, flags, (void*)out);
    } else if (ws_size >= need_R) {
        unsigned short* fullqkv = (unsigned short*)((char*)d_ws + r_full);
        unsigned short* attn    = (unsigned short*)((char*)d_ws + r_ab);
        unsigned short* WqkvT   = (unsigned short*)((char*)d_ws + r_wq);
        unsigned short* WprojT  = (unsigned short*)((char*)d_ws + r_wp);

        concat_convert_kernel<<<MTOT, 192, 0, stream>>>(xq, xs, flags, attn);
        transpose_kernel<<<dim3(QKVC / 64, DD / 64), 256, 0, stream>>>(
            qkv_w, DD, QKVC, flags, WqkvT);
        transpose_kernel<<<dim3(DD / 64, DD / 64), 256, 0, stream>>>(
            proj_w, DD, DD, flags, WprojT);
        mgemm_kernel<0, QKVC><<<dim3(QKVC / 128, MTOT / 128), 256, 0, stream>>>(
            attn, WqkvT, qkv_b, flags, (void*)fullqkv);
        fattn_kernel<0><<<BS * HH * (NN / 64), 256, 0, stream>>>(
            (const __hip_bfloat16*)fullqkv, mask, flags, (__hip_bfloat16*)attn);
        fattn_kernel<1><<<BS * HH * (PP / 64), 256, 0, stream>>>(
            (const __hip_bfloat16*)fullqkv, mask, flags, (__hip_bfloat16*)attn);
        mgemm_kernel<1, DD><<<dim3(DD / 128, MTOT / 128), 256, 0, stream>>>(
            attn, WprojT, proj_b, flags, (void*)out);
    } else {
        __hip_bfloat16* fullqkv = (__hip_bfloat16*)((char*)d_ws + 256);
        __hip_bfloat16* attn    = fullqkv + (size_t)MTOT * QKVC;
        gemm_kernel<0, QKVC, __hip_bfloat16>
            <<<dim3(QKVC / 64, MTOT / 64), 256, 0, stream>>>(
            xq, xs, qkv_w, qkv_b, flags, fullqkv);
        fattn_kernel<0><<<BS * HH * (NN / 64), 256, 0, stream>>>(fullqkv, mask, flags, attn);
        fattn_kernel<1><<<BS * HH * (PP / 64), 256, 0, stream>>>(fullqkv, mask, flags, attn);
        gemm_kernel<1, DD, float>
            <<<dim3(DD / 64, MTOT / 64), 256, 0, stream>>>(
            attn, nullptr, proj_w, proj_b, flags, out);
    }
}

// Round 13
// 241.125 us; speedup vs baseline: 32.0967x; 1.1392x over previous
//
#include <hip/hip_runtime.h>
#include <hip/hip_bf16.h>

#define BS   2
#define PP   512
#define NN   2048
#define DD   768
#define HH   12
#define HD   64
#define RTOT 2560   // P + N rows per batch
#define QKVC 2304   // 3*D
#define MTOT (BS * RTOT)       // 5120
#define CROWS (BS * HH * NN)   // 49152 cross q-rows
#define SROWS (BS * HH * PP)   // 12288 self q-rows
#define TROWS (CROWS + SROWS)  // 61440

typedef __attribute__((ext_vector_type(8))) short  short8;
typedef __attribute__((ext_vector_type(4))) float  floatx4;

#define MFMA16(a, b, c) __builtin_amdgcn_mfma_f32_16x16x32_bf16(a, b, c, 0, 0, 0)
#define LOG2E 1.4426950408889634f
#define SCL2  0.18033688011112042f   // 0.125 * log2(e)

__device__ __forceinline__ float bf2f(unsigned short x) {
    union { unsigned u; float f; } c; c.u = ((unsigned)x) << 16; return c.f;
}
__device__ __forceinline__ unsigned short f2bf(float x) {
    union { float f; unsigned u; } c; c.f = x;
    unsigned r = c.u + 0x7fff + ((c.u >> 16) & 1);   // RNE
    return (unsigned short)(r >> 16);
}

__device__ __forceinline__ float4 load4(const void* p, size_t i, bool f32) {
    if (f32) return *(const float4*)((const float*)p + i);
    ushort4 u = *(const ushort4*)((const unsigned short*)p + i);
    return make_float4(bf2f(u.x), bf2f(u.y), bf2f(u.z), bf2f(u.w));
}
__device__ __forceinline__ float load1(const void* p, size_t i, bool f32) {
    return f32 ? ((const float*)p)[i] : bf2f(((const unsigned short*)p)[i]);
}
__device__ __forceinline__ bool mask_at(const void* m, int idx, int mtype) {
    if (mtype == 2) return ((const float*)m)[idx] != 0.0f;
    if (mtype == 1) return ((const unsigned char*)m)[idx] != 0;
    return ((const int*)m)[idx] != 0;
}
__device__ __forceinline__ void store_out(float* p, size_t i, float v) { p[i] = v; }
__device__ __forceinline__ void store_out(__hip_bfloat16* p, size_t i, float v) {
    p[i] = __float2bfloat16(v);
}

// ---------------------------------------------------------------------------
// Runtime dtype detection. flags[0]: inputs f32?  flags[1]: mask type
// ---------------------------------------------------------------------------
__global__ void detect_kernel(const void* __restrict__ w,
                              const void* __restrict__ mask,
                              int* __restrict__ flags) {
    __shared__ int s_f32, s_fmask, s_bmask;
    if (threadIdx.x == 0) { s_f32 = 0; s_fmask = 0; s_bmask = 0; }
    __syncthreads();
    const unsigned short* u = (const unsigned short*)w;
    int bad = 0;
    for (int i = threadIdx.x * 2; i < 65536; i += 512) {
        float v = bf2f(u[i]);
        if (!(fabsf(v) <= 2.0f)) bad = 1;
    }
    if (bad) atomicOr(&s_f32, 1);
    const unsigned* mw = (const unsigned*)mask;
    int fm = 0, bm = 0;
    for (int i = threadIdx.x; i < 256; i += 256) {
        unsigned v = mw[i];
        if (v == 0x3F800000u) fm = 1;
        else if ((v & 0xFFFFFF00u) != 0u) bm = 1;
    }
    if (fm) atomicOr(&s_fmask, 1);
    if (bm) atomicOr(&s_bmask, 1);
    __syncthreads();
    if (threadIdx.x == 0) {
        flags[0] = s_f32;
        flags[1] = s_fmask ? 2 : (s_bmask ? 1 : 0);
    }
}

// ---------------------------------------------------------------------------
// Prep: mask -> additive LOG2-domain bias: -1e30 (masked) / -15*log2e (free).
// Fixed softmax reference: exp2(s*SCL2 - 21.64) never overflows (90-sigma).
// ---------------------------------------------------------------------------
__global__ __launch_bounds__(256) void maskbias_kernel(
    const void* __restrict__ mask, const int* __restrict__ flags,
    float* __restrict__ mb)
{
    const int mtype = flags[1];
    const int i = blockIdx.x * 256 + threadIdx.x;
    if (i >= BS * RTOT) return;
    int b = i / RTOT, m = i % RTOT;
    float v = -15.0f * LOG2E;
    if (m < PP && mask_at(mask, b * PP + m, mtype)) v = -1e30f;
    mb[i] = v;
}

// ---------------------------------------------------------------------------
// Prep: Abf[5120][768] bf16 = concat([xq, xs]) per batch.
// ---------------------------------------------------------------------------
__global__ __launch_bounds__(192) void concat_convert_kernel(
    const void* __restrict__ xq, const void* __restrict__ xs,
    const int* __restrict__ flags, unsigned short* __restrict__ Abf)
{
    const bool f32 = flags[0] != 0;
    const int r = blockIdx.x;
    const int b = r / RTOT, rr = r % RTOT;
    const void* src;
    size_t off;
    if (rr < NN) { src = xq; off = (size_t)(b * NN + rr) * DD; }
    else         { src = xs; off = (size_t)(b * PP + (rr - NN)) * DD; }
    const int t = threadIdx.x;
    float4 v = load4(src, off + t * 4, f32);
    ushort4 o;
    o.x = f2bf(v.x); o.y = f2bf(v.y); o.z = f2bf(v.z); o.w = f2bf(v.w);
    *(ushort4*)&Abf[(size_t)r * DD + t * 4] = o;
}

// ---------------------------------------------------------------------------
// Prep: out[C][R] bf16 = transpose(in[R][C]).
// ---------------------------------------------------------------------------
__global__ __launch_bounds__(256) void transpose_kernel(
    const void* __restrict__ in, int R, int C,
    const int* __restrict__ flags, unsigned short* __restrict__ out)
{
    const bool f32 = flags[0] != 0;
    __shared__ unsigned short T[64][65];
    const int c0 = blockIdx.x * 64, r0 = blockIdx.y * 64;
    const int col = threadIdx.x & 63;
    const int r4  = threadIdx.x >> 6;
    #pragma unroll
    for (int p = 0; p < 16; p++) {
        int row = p * 4 + r4;
        T[row][col] = f2bf(load1(in, (size_t)(r0 + row) * C + c0 + col, f32));
    }
    __syncthreads();
    #pragma unroll
    for (int p = 0; p < 16; p++) {
        int crow = p * 4 + r4;
        out[(size_t)(c0 + crow) * R + r0 + col] = T[col][crow];
    }
}

// ---------------------------------------------------------------------------
// Prep: VtG[(b*HH+h)][dv][m] bf16 = V^T per head, from fullqkv V block.
// ---------------------------------------------------------------------------
__global__ __launch_bounds__(256) void vtprep_kernel(
    const unsigned short* __restrict__ qkv, unsigned short* __restrict__ VtG)
{
    alignas(16) __shared__ unsigned short T[64][72];
    const int mt = blockIdx.x * 64;
    const int bh = blockIdx.y;
    const int b = bh / HH, h = bh % HH;
    const int lr  = threadIdx.x >> 2;
    const int ld0 = (threadIdx.x & 3) << 4;
    const unsigned short* vp = qkv +
        (size_t)(b * RTOT + mt + lr) * QKVC + 2 * DD + h * HD + ld0;
    *(uint4*)&T[lr][ld0]     = ((const uint4*)vp)[0];
    *(uint4*)&T[lr][ld0 + 8] = ((const uint4*)vp)[1];
    __syncthreads();
    unsigned short tmp[16];
    #pragma unroll
    for (int j = 0; j < 16; j++) tmp[j] = T[ld0 + j][lr];
    unsigned short* dst = VtG + ((size_t)bh * HD + lr) * RTOT + mt + ld0;
    *(uint4*)dst       = *(uint4*)&tmp[0];
    *(uint4*)(dst + 8) = *(uint4*)&tmp[8];
}

// ---------------------------------------------------------------------------
// MFMA GEMM: C[M][NCOL] = A @ BT^T + bias.
// ---------------------------------------------------------------------------
template<int MODE, int NCOL>
__global__ __launch_bounds__(256) void mgemm_kernel(
    const unsigned short* __restrict__ A,
    const unsigned short* __restrict__ BT,
    const void* __restrict__ bias,
    const int* __restrict__ flags,
    void* __restrict__ outp)
{
    alignas(16) __shared__ unsigned short Ash[128][72];
    alignas(16) __shared__ unsigned short Bsh[128][72];

    const int tid  = threadIdx.x;
    const int w    = tid >> 6;
    const int lane = tid & 63;
    const int grp  = lane >> 4;
    const int li   = lane & 15;
    const int row0 = blockIdx.y * 128;
    const int col0 = blockIdx.x * 128;
    const int moff = (w >> 1) * 64;
    const int noff = (w & 1) * 64;
    const int srow = tid >> 1;
    const int sseg = (tid & 1) * 32;

    floatx4 o[4][4];
    #pragma unroll
    for (int i = 0; i < 4; i++)
        #pragma unroll
        for (int j = 0; j < 4; j++)
            o[i][j] = (floatx4){0.f, 0.f, 0.f, 0.f};

    for (int k0 = 0; k0 < DD; k0 += 64) {
        const uint4* ap = (const uint4*)(A  + (size_t)(row0 + srow) * DD + k0 + sseg);
        const uint4* bp = (const uint4*)(BT + (size_t)(col0 + srow) * DD + k0 + sseg);
        uint4 a0 = ap[0], a1 = ap[1], a2 = ap[2], a3 = ap[3];
        uint4 b0 = bp[0], b1 = bp[1], b2 = bp[2], b3 = bp[3];
        __syncthreads();
        *(uint4*)&Ash[srow][sseg +  0] = a0;
        *(uint4*)&Ash[srow][sseg +  8] = a1;
        *(uint4*)&Ash[srow][sseg + 16] = a2;
        *(uint4*)&Ash[srow][sseg + 24] = a3;
        *(uint4*)&Bsh[srow][sseg +  0] = b0;
        *(uint4*)&Bsh[srow][sseg +  8] = b1;
        *(uint4*)&Bsh[srow][sseg + 16] = b2;
        *(uint4*)&Bsh[srow][sseg + 24] = b3;
        __syncthreads();
        #pragma unroll
        for (int ks = 0; ks < 2; ks++) {
            short8 af[4], bf[4];
            #pragma unroll
            for (int i = 0; i < 4; i++)
                af[i] = *(const short8*)&Ash[moff + i * 16 + li][ks * 32 + grp * 8];
            #pragma unroll
            for (int j = 0; j < 4; j++)
                bf[j] = *(const short8*)&Bsh[noff + j * 16 + li][ks * 32 + grp * 8];
            #pragma unroll
            for (int i = 0; i < 4; i++)
                #pragma unroll
                for (int j = 0; j < 4; j++)
                    o[i][j] = MFMA16(af[i], bf[j], o[i][j]);
        }
    }

    const bool f32 = flags[0] != 0;
    float bv[4];
    #pragma unroll
    for (int j = 0; j < 4; j++)
        bv[j] = load1(bias, col0 + noff + j * 16 + li, f32);

    #pragma unroll
    for (int i = 0; i < 4; i++) {
        #pragma unroll
        for (int r = 0; r < 4; r++) {
            int grow = row0 + moff + i * 16 + grp * 4 + r;
            #pragma unroll
            for (int j = 0; j < 4; j++) {
                int gcol = col0 + noff + j * 16 + li;
                float v = o[i][j][r] + bv[j];
                if (MODE == 0) {
                    ((unsigned short*)outp)[(size_t)grow * NCOL + gcol] = f2bf(v);
                } else {
                    int b = grow / RTOT, rr = grow % RTOT;
                    size_t dst = (rr < PP)
                        ? ((size_t)(b * PP + rr) * DD + gcol)
                        : ((size_t)BS * PP * DD + (size_t)(b * NN + (rr - PP)) * DD + gcol);
                    ((float*)outp)[dst] = v;
                }
            }
        }
    }
}

// ---------------------------------------------------------------------------
// fattn3: merged MFMA flash attention, 32 queries/wave (128/block),
// fixed-max log2-domain softmax, 2 barriers/tile (Psm is wave-private),
// register-prefetched K/V staging, truncating P->bf16 with bias-cancel.
// ---------------------------------------------------------------------------
template<bool PACKED, int SPL>
__global__ __launch_bounds__(256) void fattn3_kernel(
    const unsigned short* __restrict__ qkv,
    const unsigned short* __restrict__ VtG,      // used if PACKED
    const float* __restrict__ mb,                // log2-domain bias [BS*RTOT]
    unsigned short* __restrict__ attn_out,       // used if SPL==1
    unsigned short* __restrict__ part_o,         // used if SPL>1
    float* __restrict__ part_l)                  // used if SPL>1
{
    const int CB = BS * HH * (NN / 128);   // 384
    const int SB = BS * HH * (PP / 128);   // 96

    int bid = blockIdx.x;
    bool cross; int chunk, v;
    if (bid < CB * SPL) { cross = true;  chunk = bid / CB; v = bid % CB; }
    else { int s = bid - CB * SPL; cross = false; chunk = s / SB; v = s % SB; }
    const int nqb  = cross ? (NN / 128) : (PP / 128);
    const int q0   = (v % nqb) * 128;
    const int h    = (v / nqb) % HH;
    const int b    = v / (nqb * HH);
    const int QOFF = cross ? PP : 0;
    const int NT   = cross ? (RTOT / 64) : (PP / 64);
    const int tpc  = NT / SPL;
    const int t_beg = chunk * tpc, t_end = chunk * tpc + tpc;
    const int rowbase = cross ? ((b * HH + h) * NN + q0)
                              : (CROWS + (b * HH + h) * PP + q0);

    alignas(16) __shared__ unsigned short Ks[64][72];
    alignas(16) __shared__ unsigned short Vt[64][72];
    alignas(16) __shared__ unsigned short Psm[4][32][72];

    const int tid  = threadIdx.x;
    const int w    = tid >> 6;
    const int lane = tid & 63;
    const int grp  = lane >> 4;
    const int li   = lane & 15;
    const int lr   = tid >> 2;
    const int ld0  = (tid & 3) << 4;

    // Q A-frags: 2 q-tiles of 16 per wave (queries q0 + w*32 + qi*16 + li)
    short8 qf[2][2];
    #pragma unroll
    for (int qi = 0; qi < 2; qi++) {
        const unsigned short* qp = qkv +
            (size_t)(b * RTOT + QOFF + q0 + w * 32 + qi * 16 + li) * QKVC
            + h * HD + grp * 8;
        qf[qi][0] = *(const short8*)(qp);
        qf[qi][1] = *(const short8*)(qp + 32);
    }

    floatx4 o[2][4];
    #pragma unroll
    for (int qi = 0; qi < 2; qi++)
        #pragma unroll
        for (int n = 0; n < 4; n++)
            o[qi][n] = (floatx4){0.f, 0.f, 0.f, 0.f};
    float lp[2][4] = {};

    // ---- prefetch tile t_beg into registers ----
    uint4 kr0, kr1, vr0, vr1;
    {
        const unsigned short* kp = qkv +
            (size_t)(b * RTOT + t_beg * 64 + lr) * QKVC + DD + h * HD + ld0;
        kr0 = ((const uint4*)kp)[0];
        kr1 = ((const uint4*)kp)[1];
        if (PACKED) {
            const unsigned short* vp = VtG +
                ((size_t)(b * HH + h) * HD + lr) * RTOT + t_beg * 64 + ld0;
            vr0 = ((const uint4*)vp)[0];
            vr1 = ((const uint4*)vp)[1];
        } else {
            const unsigned short* vp = kp + DD;
            vr0 = ((const uint4*)vp)[0];
            vr1 = ((const uint4*)vp)[1];
        }
    }

    for (int t = t_beg; t < t_end; t++) {
        const int m0 = t * 64;
        __syncthreads();   // all waves done reading Ks/Vt of previous tile
        // ---- stage from registers ----
        *(uint4*)&Ks[lr][ld0]     = kr0;
        *(uint4*)&Ks[lr][ld0 + 8] = kr1;
        if (PACKED) {
            *(uint4*)&Vt[lr][ld0]     = vr0;
            *(uint4*)&Vt[lr][ld0 + 8] = vr1;
        } else {
            unsigned short tmp[16];
            *(uint4*)&tmp[0] = vr0;
            *(uint4*)&tmp[8] = vr1;
            #pragma unroll
            for (int j = 0; j < 16; j++) Vt[ld0 + j][lr] = tmp[j];
        }
        __syncthreads();

        // ---- prefetch next tile (overlaps compute) ----
        if (t + 1 < t_end) {
            const unsigned short* kp = qkv +
                (size_t)(b * RTOT + (t + 1) * 64 + lr) * QKVC + DD + h * HD + ld0;
            kr0 = ((const uint4*)kp)[0];
            kr1 = ((const uint4*)kp)[1];
            if (PACKED) {
                const unsigned short* vp = VtG +
                    ((size_t)(b * HH + h) * HD + lr) * RTOT + (t + 1) * 64 + ld0;
                vr0 = ((const uint4*)vp)[0];
                vr1 = ((const uint4*)vp)[1];
            } else {
                const unsigned short* vp = kp + DD;
                vr0 = ((const uint4*)vp)[0];
                vr1 = ((const uint4*)vp)[1];
            }
        }

        // ---- S = Q K^T (2 q-frags share K fragments) ----
        floatx4 sf[2][4];
        #pragma unroll
        for (int n = 0; n < 4; n++) {
            short8 kb0 = *(const short8*)&Ks[n * 16 + li][grp * 8];
            short8 kb1 = *(const short8*)&Ks[n * 16 + li][32 + grp * 8];
            #pragma unroll
            for (int qi = 0; qi < 2; qi++) {
                floatx4 acc = {0.f, 0.f, 0.f, 0.f};
                acc = MFMA16(qf[qi][0], kb0, acc);
                acc = MFMA16(qf[qi][1], kb1, acc);
                sf[qi][n] = acc;
            }
        }

        float mbv[4];
        #pragma unroll
        for (int n = 0; n < 4; n++)
            mbv[n] = mb[b * RTOT + m0 + n * 16 + li];

        // ---- fixed-max softmax in log2 domain; trunc-bf16 P, bias cancels ----
        #pragma unroll
        for (int qi = 0; qi < 2; qi++) {
            #pragma unroll
            for (int r = 0; r < 4; r++) {
                #pragma unroll
                for (int n = 0; n < 4; n++) {
                    float e = __builtin_amdgcn_exp2f(fmaf(sf[qi][n][r], SCL2, mbv[n]));
                    unsigned u = __float_as_uint(e);
                    lp[qi][r] += __uint_as_float(u & 0xffff0000u);
                    Psm[w][qi * 16 + grp * 4 + r][n * 16 + li] =
                        (unsigned short)(u >> 16);
                }
            }
        }
        // (no barrier: Psm is wave-private; in-wave ds ordering suffices)

        // ---- O += P V (V fragments shared across q-frags) ----
        #pragma unroll
        for (int s2 = 0; s2 < 2; s2++) {
            short8 pa0 = *(const short8*)&Psm[w][li][s2 * 32 + grp * 8];
            short8 pa1 = *(const short8*)&Psm[w][16 + li][s2 * 32 + grp * 8];
            #pragma unroll
            for (int n2 = 0; n2 < 4; n2++) {
                short8 vf = *(const short8*)&Vt[n2 * 16 + li][s2 * 32 + grp * 8];
                o[0][n2] = MFMA16(pa0, vf, o[0][n2]);
                o[1][n2] = MFMA16(pa1, vf, o[1][n2]);
            }
        }
    }

    // ---- one-time l reduction across 16 lanes ----
    float lfull[2][4];
    #pragma unroll
    for (int qi = 0; qi < 2; qi++)
        #pragma unroll
        for (int r = 0; r < 4; r++) {
            float l = lp[qi][r];
            #pragma unroll
            for (int off = 1; off < 16; off <<= 1)
                l += __shfl_xor(l, off);
            lfull[qi][r] = l;
        }

    // ---- epilogue ----
    if (SPL > 1) {
        #pragma unroll
        for (int qi = 0; qi < 2; qi++)
            #pragma unroll
            for (int r = 0; r < 4; r++) {
                size_t row = (size_t)chunk * TROWS + rowbase
                           + w * 32 + qi * 16 + grp * 4 + r;
                #pragma unroll
                for (int n2 = 0; n2 < 4; n2++)
                    part_o[row * 64 + n2 * 16 + li] = f2bf(o[qi][n2][r]);
                if (li == 0) part_l[row] = lfull[qi][r];
            }
    } else {
        #pragma unroll
        for (int qi = 0; qi < 2; qi++)
            #pragma unroll
            for (int r = 0; r < 4; r++) {
                float inv = 1.0f / lfull[qi][r];
                int qloc = q0 + w * 32 + qi * 16 + grp * 4 + r;
                if (cross) {
                    size_t row = (size_t)(b * RTOT + PP + qloc);
                    #pragma unroll
                    for (int n2 = 0; n2 < 4; n2++)
                        attn_out[row * DD + h * HD + n2 * 16 + li] =
                            f2bf(o[qi][n2][r] * inv);
                } else {
                    #pragma unroll
                    for (int n2 = 0; n2 < 4; n2++) {
                        int dc = n2 * 16 + li;
                        int f = h * (HD * PP) + dc * PP + qloc;
                        attn_out[(size_t)(b * RTOT + f / DD) * DD + (f % DD)]
                            = f2bf(o[qi][n2][r] * inv);
                    }
                }
            }
    }
}

// ---------------------------------------------------------------------------
// Split-K combine (fixed-max: plain sums, then normalize).
// ---------------------------------------------------------------------------
__global__ __launch_bounds__(256) void combine_kernel(
    const unsigned short* __restrict__ part_o,
    const float* __restrict__ part_l,
    unsigned short* __restrict__ attn_out)
{
    const int row = blockIdx.x * 4 + (threadIdx.x >> 6);
    const int dv  = threadIdx.x & 63;
    float l = part_l[row] + part_l[TROWS + row];
    float o1 = bf2f(part_o[(size_t)row * 64 + dv]);
    float o2 = bf2f(part_o[((size_t)TROWS + row) * 64 + dv]);
    float res = (o1 + o2) / l;
    if (row < CROWS) {
        int b = row / (HH * NN), rem = row % (HH * NN);
        int h = rem / NN, n = rem % NN;
        attn_out[(size_t)(b * RTOT + PP + n) * DD + h * HD + dv] = f2bf(res);
    } else {
        int r2 = row - CROWS;
        int b = r2 / (HH * PP), rem = r2 % (HH * PP);
        int h = rem / PP, p = rem % PP;
        int f = h * (HD * PP) + dv * PP + p;
        attn_out[(size_t)(b * RTOT + f / DD) * DD + (f % DD)] = f2bf(res);
    }
}

// ---------------------------------------------------------------------------
// Round-9 fattn (fallback tier, online softmax, reads mask directly).
// ---------------------------------------------------------------------------
template<int MODE>
__global__ __launch_bounds__(256) void fattn_kernel(
    const __hip_bfloat16* __restrict__ qkv,
    const void* __restrict__ mask,
    const int* __restrict__ flags,
    __hip_bfloat16* __restrict__ attn_out)
{
    constexpr int NQ    = (MODE == 0) ? NN : PP;
    constexpr int NK    = (MODE == 0) ? RTOT : PP;
    constexpr int QOFF  = (MODE == 0) ? PP : 0;
    constexpr int NTILE = NK / 64;

    alignas(16) __shared__ unsigned short Ks[64][72];
    alignas(16) __shared__ unsigned short Vt[64][72];
    alignas(16) __shared__ unsigned short Psm[4][16][72];

    const int tid   = threadIdx.x;
    const int w     = tid >> 6;
    const int lane  = tid & 63;
    const int grp   = lane >> 4;
    const int li    = lane & 15;
    const int nqb   = NQ / 64;
    const int q0    = (blockIdx.x % nqb) * 64;
    const int h     = (blockIdx.x / nqb) % HH;
    const int b     = blockIdx.x / (nqb * HH);
    const int mtype = flags[1];

    const unsigned short* qkv_u = (const unsigned short*)qkv;
    const int lr  = tid >> 2;
    const int ld0 = (tid & 3) << 4;

    short8 qf[2];
    {
        const unsigned short* qp = qkv_u +
            (size_t)(b * RTOT + QOFF + q0 + w * 16 + li) * QKVC + h * HD + grp * 8;
        qf[0] = *(const short8*)(qp);
        qf[1] = *(const short8*)(qp + 32);
    }

    floatx4 o[4] = {{0.f,0.f,0.f,0.f},{0.f,0.f,0.f,0.f},
                    {0.f,0.f,0.f,0.f},{0.f,0.f,0.f,0.f}};
    float mrun[4] = {-3e38f, -3e38f, -3e38f, -3e38f};
    float lrun[4] = {0.f, 0.f, 0.f, 0.f};

    for (int t = 0; t < NTILE; t++) {
        const int m0 = t * 64;
        __syncthreads();
        {
            const unsigned short* kp = qkv_u +
                (size_t)(b * RTOT + m0 + lr) * QKVC + DD + h * HD + ld0;
            *(uint4*)&Ks[lr][ld0]     = ((const uint4*)kp)[0];
            *(uint4*)&Ks[lr][ld0 + 8] = ((const uint4*)kp)[1];
            const unsigned short* vp = kp + DD;
            unsigned short tmp[16];
            *(uint4*)&tmp[0] = ((const uint4*)vp)[0];
            *(uint4*)&tmp[8] = ((const uint4*)vp)[1];
            #pragma unroll
            for (int j = 0; j < 16; j++) Vt[ld0 + j][lr] = tmp[j];
        }
        __syncthreads();

        floatx4 sf[4];
        #pragma unroll
        for (int n = 0; n < 4; n++) {
            floatx4 acc = {0.f, 0.f, 0.f, 0.f};
            short8 kb0 = *(const short8*)&Ks[n * 16 + li][grp * 8];
            short8 kb1 = *(const short8*)&Ks[n * 16 + li][32 + grp * 8];
            acc = MFMA16(qf[0], kb0, acc);
            acc = MFMA16(qf[1], kb1, acc);
            sf[n] = acc;
        }

        bool mk[4];
        #pragma unroll
        for (int n = 0; n < 4; n++) {
            int m = m0 + n * 16 + li;
            mk[n] = (m < PP) && mask_at(mask, b * PP + m, mtype);
        }

        #pragma unroll
        for (int r = 0; r < 4; r++) {
            float sv[4];
            #pragma unroll
            for (int n = 0; n < 4; n++)
                sv[n] = mk[n] ? -1e30f : sf[n][r] * 0.125f;
            float tm = fmaxf(fmaxf(sv[0], sv[1]), fmaxf(sv[2], sv[3]));
            #pragma unroll
            for (int off = 1; off < 16; off <<= 1)
                tm = fmaxf(tm, __shfl_xor(tm, off));
            float mnew = fmaxf(mrun[r], tm);
            float al = __expf(mrun[r] - mnew);
            float p[4], ts = 0.f;
            #pragma unroll
            for (int n = 0; n < 4; n++) {
                p[n] = (sv[n] < -1e29f) ? 0.f : __expf(sv[n] - mnew);
                ts += p[n];
            }
            #pragma unroll
            for (int off = 1; off < 16; off <<= 1)
                ts += __shfl_xor(ts, off);
            mrun[r] = mnew;
            lrun[r] = lrun[r] * al + ts;
            #pragma unroll
            for (int n = 0; n < 4; n++) {
                o[n][r] *= al;
                Psm[w][grp * 4 + r][n * 16 + li] = f2bf(p[n]);
            }
        }
        __syncthreads();

        #pragma unroll
        for (int s2 = 0; s2 < 2; s2++) {
            short8 pa = *(const short8*)&Psm[w][li][s2 * 32 + grp * 8];
            #pragma unroll
            for (int n2 = 0; n2 < 4; n2++) {
                short8 vf = *(const short8*)&Vt[n2 * 16 + li][s2 * 32 + grp * 8];
                o[n2] = MFMA16(pa, vf, o[n2]);
            }
        }
    }

    unsigned short* ao = (unsigned short*)attn_out;
    #pragma unroll
    for (int r = 0; r < 4; r++) {
        float inv = 1.0f / lrun[r];
        int qloc = q0 + w * 16 + grp * 4 + r;
        if (MODE == 0) {
            size_t row = (size_t)(b * RTOT + PP + qloc);
            #pragma unroll
            for (int n2 = 0; n2 < 4; n2++)
                ao[row * DD + h * HD + n2 * 16 + li] = f2bf(o[n2][r] * inv);
        } else {
            #pragma unroll
            for (int n2 = 0; n2 < 4; n2++) {
                int dc = n2 * 16 + li;
                int f = h * (HD * PP) + dc * PP + qloc;
                ao[(size_t)(b * RTOT + f / DD) * DD + (f % DD)] = f2bf(o[n2][r] * inv);
            }
        }
    }
}

// ---------------------------------------------------------------------------
// Vector GEMM fallback (last-resort tier).
// ---------------------------------------------------------------------------
template<int MODE, int NCOL, typename OutT>
__global__ __launch_bounds__(256) void gemm_kernel(
    const void* __restrict__ A0, const void* __restrict__ A1,
    const void* __restrict__ W, const void* __restrict__ bias,
    const int* __restrict__ flags, OutT* __restrict__ out)
{
    const bool f32 = flags[0] != 0;
    alignas(16) __shared__ float As[16][68];
    alignas(16) __shared__ float Bsh2[16][68];
    const int tid  = threadIdx.x;
    const int row0 = blockIdx.y * 64;
    const int col0 = blockIdx.x * 64;
    const int ty = tid >> 4, tx = tid & 15;
    const int a_row = tid >> 2;
    const int a_k4  = (tid & 3) * 4;
    const int grow  = row0 + a_row;
    const void* abase; size_t aoff; bool af32;
    if (MODE == 0) {
        int b = grow / RTOT, r = grow % RTOT;
        if (r < NN) { abase = A0; aoff = (size_t)(b * NN + r) * DD; }
        else        { abase = A1; aoff = (size_t)(b * PP + (r - NN)) * DD; }
        af32 = f32;
    } else {
        abase = A0; aoff = (size_t)grow * DD; af32 = false;
    }
    const int b_k  = tid >> 4;
    const int b_n4 = (tid & 15) * 4;
    float acc[4][4] = {};
    for (int k0 = 0; k0 < DD; k0 += 16) {
        float4 fa = load4(abase, aoff + k0 + a_k4, af32);
        As[a_k4 + 0][a_row] = fa.x;
        As[a_k4 + 1][a_row] = fa.y;
        As[a_k4 + 2][a_row] = fa.z;
        As[a_k4 + 3][a_row] = fa.w;
        float4 fb = load4(W, (size_t)(k0 + b_k) * NCOL + col0 + b_n4, f32);
        *(float4*)&Bsh2[b_k][b_n4] = fb;
        __syncthreads();
        #pragma unroll
        for (int kk = 0; kk < 16; kk++) {
            float4 av = *(const float4*)&As[kk][ty * 4];
            float4 bvv = *(const float4*)&Bsh2[kk][tx * 4];
            float a_[4] = {av.x, av.y, av.z, av.w};
            float b_[4] = {bvv.x, bvv.y, bvv.z, bvv.w};
            #pragma unroll
            for (int i = 0; i < 4; i++)
                #pragma unroll
                for (int j = 0; j < 4; j++)
                    acc[i][j] += a_[i] * b_[j];
        }
        __syncthreads();
    }
    #pragma unroll
    for (int i = 0; i < 4; i++) {
        int gr = row0 + ty * 4 + i;
        #pragma unroll
        for (int j = 0; j < 4; j++) {
            int gc = col0 + tx * 4 + j;
            float v = acc[i][j] + load1(bias, gc, f32);
            if (MODE == 0) {
                store_out(out, (size_t)gr * NCOL + gc, v);
            } else {
                int b = gr / RTOT, r = gr % RTOT;
                size_t dst = (r < PP)
                    ? ((size_t)(b * PP + r) * DD + gc)
                    : ((size_t)BS * PP * DD + (size_t)(b * NN + (r - PP)) * DD + gc);
                store_out(out, dst, v);
            }
        }
    }
}

// ---------------------------------------------------------------------------
extern "C" void kernel_launch(void* const* d_in, const int* in_sizes, int n_in,
                              void* d_out, int out_size, void* d_ws, size_t ws_size,
                              hipStream_t stream) {
    const void *xs = nullptr, *xq = nullptr, *mask = nullptr,
               *qkv_w = nullptr, *qkv_b = nullptr, *proj_w = nullptr, *proj_b = nullptr;
    for (int i = 0; i < n_in; i++) {
        switch (in_sizes[i]) {
            case BS * PP * DD:   xs     = d_in[i]; break;
            case BS * NN * DD:   xq     = d_in[i]; break;
            case BS * PP:        mask   = d_in[i]; break;
            case DD * QKVC:      qkv_w  = d_in[i]; break;
            case QKVC:           qkv_b  = d_in[i]; break;
            case DD * DD:        proj_w = d_in[i]; break;
            case DD:             proj_b = d_in[i]; break;
        }
    }
    if (!xs || !xq || !mask || !qkv_w || !qkv_b || !proj_w || !proj_b) {
        xs = d_in[0]; xq = d_in[1]; mask = d_in[2];
        qkv_w = d_in[3]; qkv_b = d_in[4]; proj_w = d_in[5]; proj_b = d_in[6];
    }
    float* out = (float*)d_out;

    const size_t off_mb   = 256;
    const size_t off_full = off_mb   + (size_t)BS * RTOT * 4;
    const size_t off_ab   = off_full + (size_t)MTOT * QKVC * 2;
    const size_t off_w    = off_ab   + (size_t)MTOT * DD * 2;
    const size_t off_wp   = off_w    + (size_t)QKVC * DD * 2;
    const size_t off_vt   = off_wp   + (size_t)DD * DD * 2;
    const size_t off_po   = off_vt   + (size_t)BS * HH * HD * RTOT * 2;
    const size_t off_ml   = off_po   + (size_t)2 * TROWS * 64 * 2;
    const size_t need_A   = off_ml   + (size_t)2 * TROWS * 4;
    const size_t need_B   = off_po;
    const size_t need_C   = off_vt;

    const size_t r_full = 256;
    const size_t r_ab   = r_full + (size_t)MTOT * QKVC * 2;
    const size_t r_wq   = r_ab   + (size_t)MTOT * DD * 2;
    const size_t r_wp   = r_wq   + (size_t)QKVC * DD * 2;
    const size_t need_R = r_wp   + (size_t)DD * DD * 2;

    int* flags = (int*)d_ws;
    detect_kernel<<<1, 256, 0, stream>>>(qkv_w, mask, flags);

    if (ws_size >= need_C) {
        float* mb               = (float*)((char*)d_ws + off_mb);
        unsigned short* fullqkv = (unsigned short*)((char*)d_ws + off_full);
        unsigned short* attn    = (unsigned short*)((char*)d_ws + off_ab);
        unsigned short* WqkvT   = (unsigned short*)((char*)d_ws + off_w);
        unsigned short* WprojT  = (unsigned short*)((char*)d_ws + off_wp);
        unsigned short* VtG     = (unsigned short*)((char*)d_ws + off_vt);
        unsigned short* part_o  = (unsigned short*)((char*)d_ws + off_po);
        float* part_l           = (float*)((char*)d_ws + off_ml);

        maskbias_kernel<<<(BS * RTOT + 255) / 256, 256, 0, stream>>>(mask, flags, mb);
        concat_convert_kernel<<<MTOT, 192, 0, stream>>>(xq, xs, flags, attn /*as Abf*/);
        transpose_kernel<<<dim3(QKVC / 64, DD / 64), 256, 0, stream>>>(
            qkv_w, DD, QKVC, flags, WqkvT);
        transpose_kernel<<<dim3(DD / 64, DD / 64), 256, 0, stream>>>(
            proj_w, DD, DD, flags, WprojT);

        mgemm_kernel<0, QKVC><<<dim3(QKVC / 128, MTOT / 128), 256, 0, stream>>>(
            attn /*Abf*/, WqkvT, qkv_b, flags, (void*)fullqkv);

        const int CB = BS * HH * (NN / 128), SB = BS * HH * (PP / 128);
        if (ws_size >= need_A) {
            vtprep_kernel<<<dim3(RTOT / 64, BS * HH), 256, 0, stream>>>(fullqkv, VtG);
            fattn3_kernel<true, 2><<<(CB + SB) * 2, 256, 0, stream>>>(
                fullqkv, VtG, mb, nullptr, part_o, part_l);
            combine_kernel<<<TROWS / 4, 256, 0, stream>>>(part_o, part_l, attn);
        } else if (ws_size >= need_B) {
            vtprep_kernel<<<dim3(RTOT / 64, BS * HH), 256, 0, stream>>>(fullqkv, VtG);
            fattn3_kernel<true, 1><<<CB + SB, 256, 0, stream>>>(
                fullqkv, VtG, mb, attn, nullptr, nullptr);
        } else {
            fattn3_kernel<false, 1><<<CB + SB, 256, 0, stream>>>(
                fullqkv, nullptr, mb, attn, nullptr, nullptr);
        }

        mgemm_kernel<1, DD><<<dim3(DD / 128, MTOT / 128), 256, 0, stream>>>(
            attn, WprojT, proj_b, flags, (void*)out);
    } else if (ws_size >= need_R) {
        unsigned short* fullqkv = (unsigned short*)((char*)d_ws + r_full);
        unsigned short* attn    = (unsigned short*)((char*)d_ws + r_ab);
        unsigned short* WqkvT   = (unsigned short*)((char*)d_ws + r_wq);
        unsigned short* WprojT  = (unsigned short*)((char*)d_ws + r_wp);

        concat_convert_kernel<<<MTOT, 192, 0, stream>>>(xq, xs, flags, attn);
        transpose_kernel<<<dim3(QKVC / 64, DD / 64), 256, 0, stream>>>(
            qkv_w, DD, QKVC, flags, WqkvT);
        transpose_kernel<<<dim3(DD / 64, DD / 64), 256, 0, stream>>>(
            proj_w, DD, DD, flags, WprojT);
        mgemm_kernel<0, QKVC><<<dim3(QKVC / 128, MTOT / 128), 256, 0, stream>>>(
            attn, WqkvT, qkv_b, flags, (void*)fullqkv);
        fattn_kernel<0><<<BS * HH * (NN / 64), 256, 0, stream>>>(
            (const __hip_bfloat16*)fullqkv, mask, flags, (__hip_bfloat16*)attn);
        fattn_kernel<1><<<BS * HH * (PP / 64), 256, 0, stream>>>(
            (const __hip_bfloat16*)fullqkv, mask, flags, (__hip_bfloat16*)attn);
        mgemm_kernel<1, DD><<<dim3(DD / 128, MTOT / 128), 256, 0, stream>>>(
            attn, WprojT, proj_b, flags, (void*)out);
    } else {
        __hip_bfloat16* fullqkv = (__hip_bfloat16*)((char*)d_ws + 256);
        __hip_bfloat16* attn    = fullqkv + (size_t)MTOT * QKVC;
        gemm_kernel<0, QKVC, __hip_bfloat16>
            <<<dim3(QKVC / 64, MTOT / 64), 256, 0, stream>>>(
            xq, xs, qkv_w, qkv_b, flags, fullqkv);
        fattn_kernel<0><<<BS * HH * (NN / 64), 256, 0, stream>>>(fullqkv, mask, flags, attn);
        fattn_kernel<1><<<BS * HH * (PP / 64), 256, 0, stream>>>(fullqkv, mask, flags, attn);
        gemm_kernel<1, DD, float>
            <<<dim3(DD / 64, MTOT / 64), 256, 0, stream>>>(
            attn, nullptr, proj_w, proj_b, flags, out);
    }
}